// Round 1
// baseline (751.474 us; speedup 1.0000x reference)
//
#include <hip/hip_runtime.h>
#include <math.h>

#define Bn 128
#define Hh 32
#define Wx 1024
#define WP 1056
#define W1O 1025

#define N1f 4198400.0f   // 128*32*1025
#define N2f 131200.0f    // 128*1025
#define N3f 33024.0f     // 128*258

// ws float offsets
#define OFF_S1_1   0
#define OFF_S2_1   16
#define OFF_A1     32
#define OFF_B1     48
#define OFF_S1_2   64
#define OFF_S2_2   96
#define OFF_S1_3   128
#define OFF_S2_3   160
#define OFF_SEG    192   // 4*33
#define OFF_CNT    324   // 4
#define OFF_MU     328   // 4*33
#define OFF_DSQ    460   // 4
#define OFF_DWOUT  512                       // 128*32*1025 = 4198400
#define OFF_POOLED (512 + 4198400)           // 128*32*256 = 1048576
#define OFF_C3     (OFF_POOLED + 1048576)    // 128*32*258 = 1056768
#define OFF_PTS    (OFF_C3 + 1056768)        // 128*64*33  = 270336
#define OFF_VO     (OFF_PTS + 270336)        // 128*64*33  = 270336

__device__ __forceinline__ float eluf(float x) { return x > 0.f ? x : expm1f(x); }

// ---------------- K1: BN1 statistics over conv1 output (recompute conv1) ----------------
__global__ __launch_bounds__(128) void k_bn1stats(const float* __restrict__ x,
                                                  const float* __restrict__ w1,
                                                  float* __restrict__ ws) {
    __shared__ float xs[WP];
    __shared__ float w1s[512];
    __shared__ float st[32];
    int tid = threadIdx.x;
    int row = blockIdx.x;  // b*32 + h
    for (int p = tid; p < WP; p += 128)
        xs[p] = (p >= 16 && p < 16 + Wx) ? x[row * Wx + (p - 16)] : 0.f;
    for (int i = tid; i < 512; i += 128) w1s[i] = w1[i];
    if (tid < 32) st[tid] = 0.f;
    __syncthreads();

    float s1[16], s2[16];
#pragma unroll
    for (int c = 0; c < 16; c++) { s1[c] = 0.f; s2[c] = 0.f; }

    for (int cb = 0; cb < 16; cb += 8) {
        float acc[8][8];
#pragma unroll
        for (int ct = 0; ct < 8; ct++)
#pragma unroll
            for (int wi = 0; wi < 8; wi++) acc[ct][wi] = 0.f;
        for (int k = 0; k < 32; k++) {
            float xv[8];
#pragma unroll
            for (int wi = 0; wi < 8; wi++) xv[wi] = xs[tid + wi * 128 + k];
#pragma unroll
            for (int ct = 0; ct < 8; ct++) {
                float wv = w1s[(cb + ct) * 32 + k];
#pragma unroll
                for (int wi = 0; wi < 8; wi++) acc[ct][wi] += xv[wi] * wv;
            }
        }
#pragma unroll
        for (int ct = 0; ct < 8; ct++)
#pragma unroll
            for (int wi = 0; wi < 8; wi++) {
                float v = acc[ct][wi];
                s1[cb + ct] += v;
                s2[cb + ct] += v * v;
            }
    }
    // tail: w = 1024
    if (tid == 0) {
#pragma unroll
        for (int c = 0; c < 16; c++) {
            float s = 0.f;
            for (int k = 0; k < 32; k++) s += xs[1024 + k] * w1s[c * 32 + k];
            s1[c] += s; s2[c] += s * s;
        }
    }
#pragma unroll
    for (int c = 0; c < 16; c++) {
        atomicAdd(&st[c], s1[c]);
        atomicAdd(&st[16 + c], s2[c]);
    }
    __syncthreads();
    if (tid < 32) atomicAdd(&ws[OFF_S1_1 + tid], st[tid]);
}

// ---------------- K1b: fold BN1 into affine coefficients ----------------
__global__ void k_bn1fold(const float* __restrict__ bn1w, const float* __restrict__ bn1b,
                          float* __restrict__ ws) {
    int c = threadIdx.x;
    if (c < 16) {
        float mean = ws[OFF_S1_1 + c] / N1f;
        float var = fmaxf(ws[OFF_S2_1 + c] / N1f - mean * mean, 0.f);
        float a = bn1w[c] / sqrtf(var + 1e-3f);
        ws[OFF_A1 + c] = a;
        ws[OFF_B1 + c] = bn1b[c] - mean * a;
    }
}

// ---------------- K2: fused conv1+bn1+dw-conv via Y-fold, plus BN2 stats ----------------
__global__ __launch_bounds__(256) void k_dw(const float* __restrict__ x,
                                            const float* __restrict__ w1,
                                            const float* __restrict__ dww,
                                            float* __restrict__ ws) {
    __shared__ float dws[1024];   // [oc][h]
    __shared__ float w1s[512];    // [g][k]
    __shared__ float Dv[32];
    __shared__ float a1s[16], b1s[16];
    __shared__ float Ys[8 * WP];
    __shared__ float st[64];
    int tid = threadIdx.x;
    int b = blockIdx.x;
    for (int i = tid; i < 1024; i += 256) dws[i] = dww[i];
    for (int i = tid; i < 512; i += 256) w1s[i] = w1[i];
    if (tid < 64) st[tid] = 0.f;
    if (tid < 16) { a1s[tid] = ws[OFF_A1 + tid]; b1s[tid] = ws[OFF_B1 + tid]; }
    __syncthreads();
    if (tid < 32) {
        float d = 0.f;
        for (int h = 0; h < 32; h++) d += dws[tid * 32 + h];
        Dv[tid] = d;
    }
    float* dwout = ws + OFF_DWOUT;
    for (int ocb = 0; ocb < 32; ocb += 8) {
        __syncthreads();
        // Phase A: Y(oc, p) = sum_h xp(b,h,p) * dw[oc,h]
        for (int p = tid; p < WP; p += 256) {
            float acc[8];
#pragma unroll
            for (int j = 0; j < 8; j++) acc[j] = 0.f;
            bool inr = (p >= 16 && p < 16 + Wx);
            const float* xb = x + b * (Hh * Wx) + (p - 16);
            for (int h = 0; h < Hh; h++) {
                float xv = inr ? xb[h * Wx] : 0.f;
#pragma unroll
                for (int j = 0; j < 8; j++) acc[j] += xv * dws[(ocb + j) * 32 + h];
            }
#pragma unroll
            for (int j = 0; j < 8; j++) Ys[j * WP + p] = acc[j];
        }
        __syncthreads();
        // Phase B: dwout(oc,w) = a_g * sum_k W1[g,k]*Y(oc,w+k) + b_g*D[oc]
        for (int j = 0; j < 8; j++) {
            int oc = ocb + j;
            int g = oc >> 1;
            float a = a1s[g], bb = b1s[g] * Dv[oc];
            float ls1 = 0.f, ls2 = 0.f;
            for (int w = tid; w < W1O; w += 256) {
                float s = 0.f;
#pragma unroll 8
                for (int k = 0; k < 32; k++) s += w1s[g * 32 + k] * Ys[j * WP + w + k];
                float val = a * s + bb;
                dwout[(b * 32 + oc) * W1O + w] = val;
                ls1 += val; ls2 += val * val;
            }
            atomicAdd(&st[oc], ls1);
            atomicAdd(&st[32 + oc], ls2);
        }
    }
    __syncthreads();
    if (tid < 64) atomicAdd(&ws[OFF_S1_2 + tid], st[tid]);
}

// ---------------- K3: BN2 apply + ELU + avgpool4 ----------------
__global__ __launch_bounds__(256) void k_pool2(const float* __restrict__ bn2w,
                                               const float* __restrict__ bn2b,
                                               float* __restrict__ ws) {
    int idx = blockIdx.x * 256 + threadIdx.x;
    if (idx >= 128 * 32 * 256) return;
    int b = idx >> 13;            // /(32*256)
    int r = idx & 8191;
    int c = r >> 8;
    int wp = r & 255;
    float mean = ws[OFF_S1_2 + c] / N2f;
    float var = fmaxf(ws[OFF_S2_2 + c] / N2f - mean * mean, 0.f);
    float a = bn2w[c] / sqrtf(var + 1e-3f);
    float bb = bn2b[c] - mean * a;
    const float* dwo = ws + OFF_DWOUT + (b * 32 + c) * W1O + wp * 4;
    float acc = 0.f;
#pragma unroll
    for (int j = 0; j < 4; j++) {
        float e = a * dwo[j] + bb;
        acc += eluf(e);
    }
    ws[OFF_POOLED + idx] = 0.25f * acc;
}

// ---------------- K4: ec1 + b2c1 (depthwise) + b2c2 (1x1 dense) + BN3 stats ----------------
__global__ __launch_bounds__(256) void k_sep(const float* __restrict__ ec1w,
                                             const float* __restrict__ bc1w,
                                             const float* __restrict__ bc2w,
                                             float* __restrict__ ws) {
    __shared__ float e2s[32 * 258];
    __shared__ float insP[4][272];
    __shared__ float e1P[4][288];
    __shared__ float ec1s[512], bc1s[512], bc2s[1024];
    __shared__ float st[64];
    int tid = threadIdx.x;
    int b = blockIdx.x;
    int wave = tid >> 6, lane = tid & 63;
    for (int i = tid; i < 512; i += 256) { ec1s[i] = ec1w[i]; bc1s[i] = bc1w[i]; }
    for (int i = tid; i < 1024; i += 256) bc2s[i] = bc2w[i];
    if (tid < 64) st[tid] = 0.f;
    for (int i = lane; i < 272; i += 64) insP[wave][i] = 0.f;
    for (int i = lane; i < 288; i += 64) e1P[wave][i] = 0.f;
    __syncthreads();
    const float* pooled = ws + OFF_POOLED + b * 8192;
    for (int it = 0; it < 8; it++) {
        int c = it * 4 + wave;
        for (int i = lane; i < 256; i += 64) insP[wave][8 + i] = pooled[c * 256 + i];
        __syncthreads();
        for (int w = lane; w < 257; w += 64) {
            float s = 0.f;
#pragma unroll
            for (int k = 0; k < 16; k++) s += insP[wave][w + k] * ec1s[c * 16 + k];
            e1P[wave][8 + w] = s;
        }
        __syncthreads();
        for (int w = lane; w < 258; w += 64) {
            float s = 0.f;
#pragma unroll
            for (int k = 0; k < 16; k++) s += e1P[wave][w + k] * bc1s[c * 16 + k];
            e2s[c * 258 + w] = s;
        }
        __syncthreads();
    }
    float* c3 = ws + OFF_C3 + b * 8256;
    for (int idx = tid; idx < 8256; idx += 256) {
        int o = idx / 258;
        int w = idx - o * 258;
        float s = 0.f;
#pragma unroll 8
        for (int cc = 0; cc < 32; cc++) s += e2s[cc * 258 + w] * bc2s[o * 32 + cc];
        c3[idx] = s;
        atomicAdd(&st[o], s);
        atomicAdd(&st[32 + o], s * s);
    }
    __syncthreads();
    if (tid < 64) atomicAdd(&ws[OFF_S1_3 + tid], st[tid]);
}

// ---------------- K5: BN3+ELU+pool4 + normalize + lift + lc1 + lift2 -> pts + domain sums ----
__global__ __launch_bounds__(256) void k_head(const float* __restrict__ bn3w,
                                              const float* __restrict__ bn3b,
                                              const float* __restrict__ lc1w,
                                              const int* __restrict__ domains,
                                              float* __restrict__ ws) {
    __shared__ float q[2048];       // [c][wp] 32x64
    __shared__ float lc1s[1089];
    __shared__ float psum[33];
    __shared__ float a3s[32], b3s[32];
    int tid = threadIdx.x;
    int b = blockIdx.x;
    if (tid < 32) {
        float mean = ws[OFF_S1_3 + tid] / N3f;
        float var = fmaxf(ws[OFF_S2_3 + tid] / N3f - mean * mean, 0.f);
        float a = bn3w[tid] / sqrtf(var + 1e-3f);
        a3s[tid] = a;
        b3s[tid] = bn3b[tid] - mean * a;
    }
    if (tid < 33) psum[tid] = 0.f;
    for (int i = tid; i < 1089; i += 256) lc1s[i] = lc1w[i];
    __syncthreads();
    const float* c3 = ws + OFF_C3 + b * 8256;
    for (int idx = tid; idx < 2048; idx += 256) {
        int c = idx >> 6, wp = idx & 63;
        float a = a3s[c], bb = b3s[c];
        float acc = 0.f;
#pragma unroll
        for (int j = 0; j < 4; j++) {
            float e = a * c3[c * 258 + wp * 4 + j] + bb;
            acc += eluf(e);
        }
        q[idx] = 0.25f * acc;
    }
    __syncthreads();
    int dom = domains[b];
    if (tid < 64) {
        int w = tid;
        float v[32];
        float ss = 0.f;
#pragma unroll
        for (int c = 0; c < 32; c++) { v[c] = q[c * 64 + w]; ss += v[c] * v[c]; }
        float nrm = fmaxf(sqrtf(ss), 1e-12f);
        float inv = 1.f / nrm;
        float ss2 = 0.f;
#pragma unroll
        for (int c = 0; c < 32; c++) { v[c] *= inv; ss2 += v[c] * v[c]; }
        float t = sqrtf(1.f + ss2);
        float p[33];
#pragma unroll
        for (int o = 0; o < 33; o++) {
            float s = lc1s[o * 33] * t;
#pragma unroll
            for (int c = 0; c < 32; c++) s += lc1s[o * 33 + 1 + c] * v[c];
            p[o] = s;
        }
        float ssy = 0.f;
#pragma unroll
        for (int o = 1; o < 33; o++) ssy += p[o] * p[o];
        float yt = sqrtf(1.f + ssy);
        float* pr = ws + OFF_PTS + (b * 64 + w) * 33;
        pr[0] = yt;
        atomicAdd(&psum[0], yt);
#pragma unroll
        for (int o = 1; o < 33; o++) { pr[o] = p[o]; atomicAdd(&psum[o], p[o]); }
    }
    __syncthreads();
    if (tid < 33) atomicAdd(&ws[OFF_SEG + dom * 33 + tid], psum[tid]);
    if (tid == 0) atomicAdd(&ws[OFF_CNT + dom], 64.f);
}

// ---------------- K6: per-domain Frechet-ish mean mu ----------------
__global__ void k_mu(float* __restrict__ ws) {
    int d = threadIdx.x;
    if (d < 4) {
        float cnt = fmaxf(ws[OFF_CNT + d], 1.f);
        float s0 = ws[OFF_SEG + d * 33] / cnt;
        float sv[33];
        sv[0] = s0;
        float sum = 0.f;
        for (int c = 1; c < 33; c++) {
            sv[c] = ws[OFF_SEG + d * 33 + c] / cnt;
            sum += sv[c] * sv[c];
        }
        float mk = -s0 * s0 + sum;
        float dn = sqrtf(fmaxf(fabsf(mk), 1e-8f));
        for (int c = 0; c < 33; c++) ws[OFF_MU + d * 33 + c] = sv[c] / dn;
    }
}

// ---------------- K7: log-map at mu, transport to origin, dist^2 sums ----------------
__global__ __launch_bounds__(64) void k_tangent(const int* __restrict__ domains,
                                                float* __restrict__ ws) {
    int b = blockIdx.x;
    int w = threadIdx.x;
    int dom = domains[b];
    const float* mu = ws + OFF_MU + dom * 33;
    const float* pr = ws + OFF_PTS + (b * 64 + w) * 33;
    float m[33], p[33];
#pragma unroll
    for (int c = 0; c < 33; c++) { m[c] = mu[c]; p[c] = pr[c]; }
    float ip = -m[0] * p[0];
#pragma unroll
    for (int c = 1; c < 33; c++) ip += m[c] * p[c];
    float z = fmaxf(-ip, 1.f + 1e-7f);
    float dist = acoshf(z);
    float u[33];
#pragma unroll
    for (int c = 0; c < 33; c++) u[c] = p[c] + ip * m[c];
    float mk = -u[0] * u[0];
#pragma unroll
    for (int c = 1; c < 33; c++) mk += u[c] * u[c];
    float un = sqrtf(fmaxf(mk, 1e-8f));
    float r = dist / un;
    float v0 = r * u[0];
    float coef = -v0 / (1.f + m[0]);
    float* vo = ws + OFF_VO + (b * 64 + w) * 33;
    vo[0] = v0 + coef * (m[0] + 1.f);
#pragma unroll
    for (int c = 1; c < 33; c++) vo[c] = r * u[c] + coef * m[c];
    float dsq = dist * dist;
#pragma unroll
    for (int off = 32; off > 0; off >>= 1) dsq += __shfl_down(dsq, off);
    if (w == 0) atomicAdd(&ws[OFF_DSQ + dom], dsq);
}

// ---------------- K8: scale, transport to beta, expmap, Lorentz ELU, Lorentz pool, MLR ----
__global__ __launch_bounds__(64) void k_final(const int* __restrict__ domains,
                                              const float* __restrict__ beta,
                                              const float* __restrict__ gamma,
                                              const float* __restrict__ mlr_a,
                                              const float* __restrict__ mlr_z,
                                              float* __restrict__ ws,
                                              float* __restrict__ out) {
    __shared__ float he[64 * 33];
    __shared__ float hp[16 * 33];
    int b = blockIdx.x;
    int w = threadIdx.x;
    int dom = domains[b];
    float cnt = fmaxf(ws[OFF_CNT + dom], 1.f);
    float var = ws[OFF_DSQ + dom] / cnt;
    float sc = gamma[0] / sqrtf(var + 1e-5f);
    float bt[33];
#pragma unroll
    for (int c = 0; c < 33; c++) bt[c] = beta[c];
    const float* vo = ws + OFF_VO + (b * 64 + w) * 33;
    float v[33];
#pragma unroll
    for (int c = 0; c < 33; c++) v[c] = vo[c] * sc;
    float mb = -bt[0] * v[0];
#pragma unroll
    for (int c = 1; c < 33; c++) mb += bt[c] * v[c];
    float coef = mb / (1.f + bt[0]);
    v[0] += coef * (1.f + bt[0]);
#pragma unroll
    for (int c = 1; c < 33; c++) v[c] += coef * bt[c];
    float mk = -v[0] * v[0];
#pragma unroll
    for (int c = 1; c < 33; c++) mk += v[c] * v[c];
    float vn = sqrtf(fmaxf(mk, 1e-8f));
    float ch = coshf(vn), sh = sinhf(vn) / vn;
    float ss = 0.f;
#pragma unroll
    for (int c = 1; c < 33; c++) {
        float y = ch * bt[c] + sh * v[c];
        float s = eluf(y);
        he[w * 33 + c] = s;
        ss += s * s;
    }
    he[w * 33] = sqrtf(1.f + ss);
    __syncthreads();
    if (w < 16) {
        float tmp[33];
        float mk2;
        {
            float a0 = 0.25f * (he[(4 * w) * 33] + he[(4 * w + 1) * 33] + he[(4 * w + 2) * 33] + he[(4 * w + 3) * 33]);
            tmp[0] = a0;
            mk2 = -a0 * a0;
        }
#pragma unroll
        for (int c = 1; c < 33; c++) {
            float a = 0.25f * (he[(4 * w) * 33 + c] + he[(4 * w + 1) * 33 + c] +
                               he[(4 * w + 2) * 33 + c] + he[(4 * w + 3) * 33 + c]);
            tmp[c] = a;
            mk2 += a * a;
        }
        float dd = sqrtf(fmaxf(fabsf(mk2), 1e-8f));
#pragma unroll
        for (int c = 0; c < 33; c++) hp[w * 33 + c] = tmp[c] / dd;
    }
    __syncthreads();
    float ssq = 0.f, sdz = 0.f, zz = 0.f;
    for (int j = w; j < 512; j += 64) {
        float val = hp[(j >> 5) * 33 + 1 + (j & 31)];
        float zv = mlr_z[j];
        ssq += val * val;
        sdz += val * zv;
        zz += zv * zv;
        out[128 + b * 513 + 1 + j] = val;
    }
#pragma unroll
    for (int off = 32; off > 0; off >>= 1) {
        ssq += __shfl_down(ssq, off);
        sdz += __shfl_down(sdz, off);
        zz += __shfl_down(zz, off);
    }
    if (w == 0) {
        float nz = sqrtf(zz);
        float a = mlr_a[0];
        float cha = coshf(a);
        float wt = sinhf(a) * nz;
        float cn = cha * nz;
        float bet = sqrtf(fmaxf(cn * cn - wt * wt, 1e-8f));
        float ft = sqrtf(1.f + ssq);
        float alpha = -wt * ft + cha * sdz;
        out[128 + b * 513] = ft;
        out[b] = bet * asinhf(alpha / bet);
    }
}

extern "C" void kernel_launch(void* const* d_in, const int* in_sizes, int n_in,
                              void* d_out, int out_size, void* d_ws, size_t ws_size,
                              hipStream_t stream) {
    const float* x       = (const float*)d_in[0];
    const int*   domains = (const int*)d_in[1];
    const float* conv1_w = (const float*)d_in[2];
    const float* bn1_w   = (const float*)d_in[3];
    const float* bn1_b   = (const float*)d_in[4];
    const float* dw_w    = (const float*)d_in[5];
    const float* bn2_w   = (const float*)d_in[6];
    const float* bn2_b   = (const float*)d_in[7];
    const float* ec1_w   = (const float*)d_in[8];
    const float* b2c1_w  = (const float*)d_in[9];
    const float* b2c2_w  = (const float*)d_in[10];
    const float* bn3_w   = (const float*)d_in[11];
    const float* bn3_b   = (const float*)d_in[12];
    const float* lc1_w   = (const float*)d_in[13];
    const float* bn_beta = (const float*)d_in[14];
    const float* bn_gamma= (const float*)d_in[15];
    const float* mlr_a   = (const float*)d_in[16];
    const float* mlr_z   = (const float*)d_in[17];
    float* out = (float*)d_out;
    float* ws  = (float*)d_ws;

    hipMemsetAsync(ws, 0, 512 * sizeof(float), stream);
    k_bn1stats<<<Bn * Hh, 128, 0, stream>>>(x, conv1_w, ws);
    k_bn1fold<<<1, 64, 0, stream>>>(bn1_w, bn1_b, ws);
    k_dw<<<Bn, 256, 0, stream>>>(x, conv1_w, dw_w, ws);
    k_pool2<<<(128 * 32 * 256) / 256, 256, 0, stream>>>(bn2_w, bn2_b, ws);
    k_sep<<<Bn, 256, 0, stream>>>(ec1_w, b2c1_w, b2c2_w, ws);
    k_head<<<Bn, 256, 0, stream>>>(bn3_w, bn3_b, lc1_w, domains, ws);
    k_mu<<<1, 64, 0, stream>>>(ws);
    k_tangent<<<Bn, 64, 0, stream>>>(domains, ws);
    k_final<<<Bn, 64, 0, stream>>>(domains, bn_beta, bn_gamma, mlr_a, mlr_z, ws, out);
}

// Round 2
// 369.374 us; speedup vs baseline: 2.0345x; 2.0345x over previous
//
#include <hip/hip_runtime.h>
#include <math.h>

#define Bn 128
#define Hh 32
#define Wx 1024
#define WP 1056
#define W1O 1025

#define N1f 4198400.0f   // 128*32*1025
#define N2f 131200.0f    // 128*1025
#define N3f 33024.0f     // 128*258

// ---- ws float offsets ----
#define OFF_C      0     // 32  autocorr C[d]
#define OFF_S      32    // 1   total sum of x
#define OFF_EH     33    // 15  E[j] head j=0..14
#define OFF_ET     48    // 15  E[1009+j]
#define OFF_G      64    // 480 G[d*15+j], j head
#define OFF_G2     544   // 480 G2[d*15+j], j tail (x[1009+j]*x[1009+j+d])
#define OFF_A1     1024  // 16
#define OFF_B1     1040  // 16
#define OFF_S1_2   1056  // 32
#define OFF_S2_2   1088  // 32
#define OFF_S1_3   1120  // 32
#define OFF_S2_3   1152  // 32
#define OFF_SEG    1184  // 132
#define OFF_CNT    1316  // 4
#define OFF_MU     1320  // 132
#define OFF_DSQ    1452  // 4
#define ZERO_N     1456
#define OFF_DWOUT  2048                      // 128*32*1025 = 4198400
#define OFF_POOLED (2048 + 4198400)          // 128*32*256  = 1048576
// DWOUT region is dead after k_pool2 -> overlay later tensors there
#define OFF_C3     OFF_DWOUT                 // 128*32*258 = 1056768
#define OFF_PTS    (OFF_C3 + 1056768)        // 128*64*33  = 270336
#define OFF_VO     (OFF_PTS + 270336)        // 128*64*33  = 270336

__device__ __forceinline__ float eluf(float x) { return x > 0.f ? x : expm1f(x); }

// ---------------- K1: lag-autocorrelation statistics of x ----------------
// Per 16 rows: C[d]=sum_j x[j]x[j+d]; edge sums G,G2,EH,ET; total S.
__global__ __launch_bounds__(256) void k_corr(const float* __restrict__ x,
                                              float* __restrict__ ws) {
    __shared__ float xs[1060];
    __shared__ float cacc[32];
    __shared__ float gacc[480];
    __shared__ float g2acc[480];
    __shared__ float eacc[30];
    int tid = threadIdx.x;
    for (int i = tid; i < 480; i += 256) { gacc[i] = 0.f; g2acc[i] = 0.f; }
    if (tid < 32) cacc[tid] = 0.f;
    if (tid < 30) eacc[tid] = 0.f;
    for (int i = 1024 + tid; i < 1060; i += 256) xs[i] = 0.f;
    float acc[32];
#pragma unroll
    for (int d = 0; d < 32; d++) acc[d] = 0.f;
    float sp = 0.f;
    int r0 = blockIdx.x * 16;
    for (int rr = 0; rr < 16; rr++) {
        __syncthreads();
        const float4* xr = (const float4*)(x + (r0 + rr) * Wx);
        ((float4*)xs)[tid] = xr[tid];
        __syncthreads();
        float v[36];
#pragma unroll
        for (int q = 0; q < 9; q++) {
            float4 t4 = ((const float4*)xs)[tid + q];
            v[4 * q] = t4.x; v[4 * q + 1] = t4.y; v[4 * q + 2] = t4.z; v[4 * q + 3] = t4.w;
        }
#pragma unroll
        for (int i = 0; i < 4; i++) {
            sp += v[i];
#pragma unroll
            for (int d = 0; d < 32; d++) acc[d] += v[i] * v[i + d];
        }
        if (tid < 240) {
#pragma unroll
            for (int q = 0; q < 2; q++) {
                int idx = tid * 2 + q;
                int d = idx / 15, j = idx - d * 15;
                gacc[idx]  += xs[j] * xs[j + d];
                g2acc[idx] += xs[1009 + j] * xs[1009 + j + d];
            }
        } else if (tid < 270) {
            int j = tid - 240;
            eacc[j] += (j < 15) ? xs[j] : xs[1009 + (j - 15)];
        }
    }
    int lane = tid & 63;
#pragma unroll
    for (int d = 0; d < 32; d++) {
        float vv = acc[d];
#pragma unroll
        for (int off = 32; off > 0; off >>= 1) vv += __shfl_down(vv, off);
        if (lane == 0) atomicAdd(&cacc[d], vv);
    }
    {
        float vv = sp;
#pragma unroll
        for (int off = 32; off > 0; off >>= 1) vv += __shfl_down(vv, off);
        if (lane == 0) atomicAdd(&ws[OFF_S], vv);
    }
    __syncthreads();
    if (tid < 32) atomicAdd(&ws[OFF_C + tid], cacc[tid]);
    for (int i = tid; i < 480; i += 256) {
        atomicAdd(&ws[OFF_G + i], gacc[i]);
        atomicAdd(&ws[OFF_G2 + i], g2acc[i]);
    }
    if (tid < 30) atomicAdd(&ws[OFF_EH + tid], eacc[tid]);  // EH then ET contiguous
}

// ---------------- K1b: assemble BN1 mean/var from correlations ----------------
__global__ __launch_bounds__(512) void k_fold(const float* __restrict__ w1,
                                              const float* __restrict__ bn1w,
                                              const float* __restrict__ bn1b,
                                              float* __restrict__ ws) {
    __shared__ float PH[32][16];
    __shared__ float PT[32][16];
    __shared__ float Ts[32];
    __shared__ float w1s[512];
    __shared__ float sumsq[16];
    __shared__ float meanv[16];
    int tid = threadIdx.x;
    w1s[tid] = w1[tid];
    if (tid < 16) sumsq[tid] = 0.f;
    if (tid < 32) {
        int d = tid;
        float s = 0.f;
        for (int j = 0; j < 15; j++) { s += ws[OFF_G + d * 15 + j]; PH[d][j] = s; }
        float s2 = 0.f;
        for (int j = 14; j >= 0; j--) { s2 += ws[OFF_G2 + d * 15 + j]; PT[d][j] = s2; }
    } else if (tid >= 64 && tid < 96) {
        int k = tid - 64;
        float t = ws[OFF_S];
        for (int j = 0; j <= k - 17; j++) t -= ws[OFF_EH + j];
        if (k <= 14) for (int j = k; j < 15; j++) t -= ws[OFF_ET + j];
        Ts[k] = t;
    }
    __syncthreads();
    int c = tid >> 5, d = tid & 31;
    float Cd = ws[OFF_C + d];
    float part = 0.f;
    for (int k = 0; k + d < 32; k++) {
        float head = (k >= 17) ? PH[d][k - 17] : 0.f;
        float tail = (k <= 14) ? PT[d][k] : 0.f;
        float R = Cd - head - tail;
        part += w1s[c * 32 + k] * w1s[c * 32 + k + d] * R;
    }
    if (d > 0) part *= 2.f;
    atomicAdd(&sumsq[c], part);
    if (d == 0) {
        float mp = 0.f;
        for (int k = 0; k < 32; k++) mp += w1s[c * 32 + k] * Ts[k];
        meanv[c] = mp / N1f;
    }
    __syncthreads();
    if (tid < 16) {
        float mean = meanv[tid];
        float var = fmaxf(sumsq[tid] / N1f - mean * mean, 0.f);
        float a = bn1w[tid] / sqrtf(var + 1e-3f);
        ws[OFF_A1 + tid] = a;
        ws[OFF_B1 + tid] = bn1b[tid] - mean * a;
    }
}

// ---------------- K2: fused conv1+bn1+dw-conv via Y-fold, plus BN2 stats ----------------
// grid (128, 4): block handles batch b, output channels [8*y, 8*y+8)
__global__ __launch_bounds__(256) void k_dw(const float* __restrict__ x,
                                            const float* __restrict__ w1,
                                            const float* __restrict__ dww,
                                            float* __restrict__ ws) {
    __shared__ float dws[256];   // 8 oc x 32 h
    __shared__ float w1s[128];   // 4 groups x 32
    __shared__ float Dv[8];
    __shared__ float a1s[4], b1s[4];
    __shared__ float Ys[8 * WP];
    __shared__ float st[16];
    int tid = threadIdx.x;
    int b = blockIdx.x;
    int ocb = blockIdx.y * 8;
    int g0 = ocb >> 1;
    dws[tid] = dww[ocb * 32 + tid];
    if (tid < 128) w1s[tid] = w1[g0 * 32 + tid];
    if (tid < 16) st[tid] = 0.f;
    if (tid < 4) { a1s[tid] = ws[OFF_A1 + g0 + tid]; b1s[tid] = ws[OFF_B1 + g0 + tid]; }
    __syncthreads();
    if (tid < 8) {
        float d = 0.f;
        for (int h = 0; h < 32; h++) d += dws[tid * 32 + h];
        Dv[tid] = d;
    }
    // Phase A: Y(j, p) = sum_h xpad(b,h,p) * dw[ocb+j, h]
    for (int p = tid; p < WP; p += 256) {
        float acc[8];
#pragma unroll
        for (int j = 0; j < 8; j++) acc[j] = 0.f;
        bool inr = (p >= 16 && p < 16 + Wx);
        const float* xb = x + b * (Hh * Wx) + (p - 16);
        for (int h = 0; h < Hh; h++) {
            float xv = inr ? xb[h * Wx] : 0.f;
#pragma unroll
            for (int j = 0; j < 8; j++) acc[j] += xv * dws[j * 32 + h];
        }
#pragma unroll
        for (int j = 0; j < 8; j++) Ys[j * WP + p] = acc[j];
    }
    __syncthreads();
    float* dwout = ws + OFF_DWOUT;
    int lane = tid & 63;
    for (int j = 0; j < 8; j++) {
        int oc = ocb + j;
        int gl = j >> 1;
        float a = a1s[gl], bb = b1s[gl] * Dv[j];
        float ls1 = 0.f, ls2 = 0.f;
        for (int w = tid; w < W1O; w += 256) {
            float s = 0.f;
#pragma unroll 8
            for (int k = 0; k < 32; k++) s += w1s[gl * 32 + k] * Ys[j * WP + w + k];
            float val = a * s + bb;
            dwout[(b * 32 + oc) * W1O + w] = val;
            ls1 += val; ls2 += val * val;
        }
#pragma unroll
        for (int off = 32; off > 0; off >>= 1) {
            ls1 += __shfl_down(ls1, off);
            ls2 += __shfl_down(ls2, off);
        }
        if (lane == 0) { atomicAdd(&st[j], ls1); atomicAdd(&st[8 + j], ls2); }
    }
    __syncthreads();
    if (tid < 8) atomicAdd(&ws[OFF_S1_2 + ocb + tid], st[tid]);
    else if (tid < 16) atomicAdd(&ws[OFF_S2_2 + ocb + tid - 8], st[tid]);
}

// ---------------- K3: BN2 apply + ELU + avgpool4 ----------------
__global__ __launch_bounds__(256) void k_pool2(const float* __restrict__ bn2w,
                                               const float* __restrict__ bn2b,
                                               float* __restrict__ ws) {
    int idx = blockIdx.x * 256 + threadIdx.x;
    if (idx >= 128 * 32 * 256) return;
    int b = idx >> 13;
    int r = idx & 8191;
    int c = r >> 8;
    int wp = r & 255;
    float mean = ws[OFF_S1_2 + c] / N2f;
    float var = fmaxf(ws[OFF_S2_2 + c] / N2f - mean * mean, 0.f);
    float a = bn2w[c] / sqrtf(var + 1e-3f);
    float bb = bn2b[c] - mean * a;
    const float* dwo = ws + OFF_DWOUT + (b * 32 + c) * W1O + wp * 4;
    float acc = 0.f;
#pragma unroll
    for (int j = 0; j < 4; j++) {
        float e = a * dwo[j] + bb;
        acc += eluf(e);
    }
    ws[OFF_POOLED + idx] = 0.25f * acc;
}

// ---------------- K4: ec1 + b2c1 (depthwise) + b2c2 (1x1 dense) + BN3 stats ----------------
__global__ __launch_bounds__(256) void k_sep(const float* __restrict__ ec1w,
                                             const float* __restrict__ bc1w,
                                             const float* __restrict__ bc2w,
                                             float* __restrict__ ws) {
    __shared__ float e2s[32 * 258];
    __shared__ float insP[4][272];
    __shared__ float e1P[4][288];
    __shared__ float ec1s[512], bc1s[512], bc2s[1024];
    __shared__ float st[64];
    int tid = threadIdx.x;
    int b = blockIdx.x;
    int wave = tid >> 6, lane = tid & 63;
    for (int i = tid; i < 512; i += 256) { ec1s[i] = ec1w[i]; bc1s[i] = bc1w[i]; }
    for (int i = tid; i < 1024; i += 256) bc2s[i] = bc2w[i];
    if (tid < 64) st[tid] = 0.f;
    for (int i = lane; i < 272; i += 64) insP[wave][i] = 0.f;
    for (int i = lane; i < 288; i += 64) e1P[wave][i] = 0.f;
    __syncthreads();
    const float* pooled = ws + OFF_POOLED + b * 8192;
    for (int it = 0; it < 8; it++) {
        int c = it * 4 + wave;
        for (int i = lane; i < 256; i += 64) insP[wave][8 + i] = pooled[c * 256 + i];
        __syncthreads();
        for (int w = lane; w < 257; w += 64) {
            float s = 0.f;
#pragma unroll
            for (int k = 0; k < 16; k++) s += insP[wave][w + k] * ec1s[c * 16 + k];
            e1P[wave][8 + w] = s;
        }
        __syncthreads();
        for (int w = lane; w < 258; w += 64) {
            float s = 0.f;
#pragma unroll
            for (int k = 0; k < 16; k++) s += e1P[wave][w + k] * bc1s[c * 16 + k];
            e2s[c * 258 + w] = s;
        }
        __syncthreads();
    }
    float* c3 = ws + OFF_C3 + b * 8256;
    for (int idx = tid; idx < 8256; idx += 256) {
        int o = idx / 258;
        int w = idx - o * 258;
        float s = 0.f;
#pragma unroll 8
        for (int cc = 0; cc < 32; cc++) s += e2s[cc * 258 + w] * bc2s[o * 32 + cc];
        c3[idx] = s;
        atomicAdd(&st[o], s);
        atomicAdd(&st[32 + o], s * s);
    }
    __syncthreads();
    if (tid < 64) atomicAdd(&ws[OFF_S1_3 + tid], st[tid]);
}

// ---------------- K5: BN3+ELU+pool4 + normalize + lift + lc1 + lift2 -> pts ----------------
__global__ __launch_bounds__(256) void k_head(const float* __restrict__ bn3w,
                                              const float* __restrict__ bn3b,
                                              const float* __restrict__ lc1w,
                                              const int* __restrict__ domains,
                                              float* __restrict__ ws) {
    __shared__ float q[2048];
    __shared__ float lc1s[1089];
    __shared__ float psum[33];
    __shared__ float a3s[32], b3s[32];
    int tid = threadIdx.x;
    int b = blockIdx.x;
    if (tid < 32) {
        float mean = ws[OFF_S1_3 + tid] / N3f;
        float var = fmaxf(ws[OFF_S2_3 + tid] / N3f - mean * mean, 0.f);
        float a = bn3w[tid] / sqrtf(var + 1e-3f);
        a3s[tid] = a;
        b3s[tid] = bn3b[tid] - mean * a;
    }
    if (tid < 33) psum[tid] = 0.f;
    for (int i = tid; i < 1089; i += 256) lc1s[i] = lc1w[i];
    __syncthreads();
    const float* c3 = ws + OFF_C3 + b * 8256;
    for (int idx = tid; idx < 2048; idx += 256) {
        int c = idx >> 6, wp = idx & 63;
        float a = a3s[c], bb = b3s[c];
        float acc = 0.f;
#pragma unroll
        for (int j = 0; j < 4; j++) {
            float e = a * c3[c * 258 + wp * 4 + j] + bb;
            acc += eluf(e);
        }
        q[idx] = 0.25f * acc;
    }
    __syncthreads();
    int dom = domains[b];
    if (tid < 64) {
        int w = tid;
        float v[32];
        float ss = 0.f;
#pragma unroll
        for (int c = 0; c < 32; c++) { v[c] = q[c * 64 + w]; ss += v[c] * v[c]; }
        float nrm = fmaxf(sqrtf(ss), 1e-12f);
        float inv = 1.f / nrm;
        float ss2 = 0.f;
#pragma unroll
        for (int c = 0; c < 32; c++) { v[c] *= inv; ss2 += v[c] * v[c]; }
        float t = sqrtf(1.f + ss2);
        float p[33];
#pragma unroll
        for (int o = 0; o < 33; o++) {
            float s = lc1s[o * 33] * t;
#pragma unroll
            for (int c = 0; c < 32; c++) s += lc1s[o * 33 + 1 + c] * v[c];
            p[o] = s;
        }
        float ssy = 0.f;
#pragma unroll
        for (int o = 1; o < 33; o++) ssy += p[o] * p[o];
        float yt = sqrtf(1.f + ssy);
        float* pr = ws + OFF_PTS + (b * 64 + w) * 33;
        pr[0] = yt;
        atomicAdd(&psum[0], yt);
#pragma unroll
        for (int o = 1; o < 33; o++) { pr[o] = p[o]; atomicAdd(&psum[o], p[o]); }
    }
    __syncthreads();
    if (tid < 33) atomicAdd(&ws[OFF_SEG + dom * 33 + tid], psum[tid]);
    if (tid == 0) atomicAdd(&ws[OFF_CNT + dom], 64.f);
}

// ---------------- K6: per-domain mean mu ----------------
__global__ void k_mu(float* __restrict__ ws) {
    int d = threadIdx.x;
    if (d < 4) {
        float cnt = fmaxf(ws[OFF_CNT + d], 1.f);
        float sv[33];
        float s0 = ws[OFF_SEG + d * 33] / cnt;
        sv[0] = s0;
        float sum = 0.f;
        for (int c = 1; c < 33; c++) {
            sv[c] = ws[OFF_SEG + d * 33 + c] / cnt;
            sum += sv[c] * sv[c];
        }
        float mk = -s0 * s0 + sum;
        float dn = sqrtf(fmaxf(fabsf(mk), 1e-8f));
        for (int c = 0; c < 33; c++) ws[OFF_MU + d * 33 + c] = sv[c] / dn;
    }
}

// ---------------- K7: log-map at mu, transport to origin, dist^2 sums ----------------
__global__ __launch_bounds__(64) void k_tangent(const int* __restrict__ domains,
                                                float* __restrict__ ws) {
    int b = blockIdx.x;
    int w = threadIdx.x;
    int dom = domains[b];
    const float* mu = ws + OFF_MU + dom * 33;
    const float* pr = ws + OFF_PTS + (b * 64 + w) * 33;
    float m[33], p[33];
#pragma unroll
    for (int c = 0; c < 33; c++) { m[c] = mu[c]; p[c] = pr[c]; }
    float ip = -m[0] * p[0];
#pragma unroll
    for (int c = 1; c < 33; c++) ip += m[c] * p[c];
    float z = fmaxf(-ip, 1.f + 1e-7f);
    float dist = acoshf(z);
    float u[33];
#pragma unroll
    for (int c = 0; c < 33; c++) u[c] = p[c] + ip * m[c];
    float mk = -u[0] * u[0];
#pragma unroll
    for (int c = 1; c < 33; c++) mk += u[c] * u[c];
    float un = sqrtf(fmaxf(mk, 1e-8f));
    float r = dist / un;
    float v0 = r * u[0];
    float coef = -v0 / (1.f + m[0]);
    float* vo = ws + OFF_VO + (b * 64 + w) * 33;
    vo[0] = v0 + coef * (m[0] + 1.f);
#pragma unroll
    for (int c = 1; c < 33; c++) vo[c] = r * u[c] + coef * m[c];
    float dsq = dist * dist;
#pragma unroll
    for (int off = 32; off > 0; off >>= 1) dsq += __shfl_down(dsq, off);
    if (w == 0) atomicAdd(&ws[OFF_DSQ + dom], dsq);
}

// ---------------- K8: scale, transport to beta, expmap, L-ELU, L-pool, MLR ----------------
__global__ __launch_bounds__(64) void k_final(const int* __restrict__ domains,
                                              const float* __restrict__ beta,
                                              const float* __restrict__ gamma,
                                              const float* __restrict__ mlr_a,
                                              const float* __restrict__ mlr_z,
                                              float* __restrict__ ws,
                                              float* __restrict__ out) {
    __shared__ float he[64 * 33];
    __shared__ float hp[16 * 33];
    int b = blockIdx.x;
    int w = threadIdx.x;
    int dom = domains[b];
    float cnt = fmaxf(ws[OFF_CNT + dom], 1.f);
    float var = ws[OFF_DSQ + dom] / cnt;
    float sc = gamma[0] / sqrtf(var + 1e-5f);
    float bt[33];
#pragma unroll
    for (int c = 0; c < 33; c++) bt[c] = beta[c];
    const float* vo = ws + OFF_VO + (b * 64 + w) * 33;
    float v[33];
#pragma unroll
    for (int c = 0; c < 33; c++) v[c] = vo[c] * sc;
    float mb = -bt[0] * v[0];
#pragma unroll
    for (int c = 1; c < 33; c++) mb += bt[c] * v[c];
    float coef = mb / (1.f + bt[0]);
    v[0] += coef * (1.f + bt[0]);
#pragma unroll
    for (int c = 1; c < 33; c++) v[c] += coef * bt[c];
    float mk = -v[0] * v[0];
#pragma unroll
    for (int c = 1; c < 33; c++) mk += v[c] * v[c];
    float vn = sqrtf(fmaxf(mk, 1e-8f));
    float ch = coshf(vn), sh = sinhf(vn) / vn;
    float ss = 0.f;
#pragma unroll
    for (int c = 1; c < 33; c++) {
        float y = ch * bt[c] + sh * v[c];
        float s = eluf(y);
        he[w * 33 + c] = s;
        ss += s * s;
    }
    he[w * 33] = sqrtf(1.f + ss);
    __syncthreads();
    if (w < 16) {
        float tmp[33];
        float mk2;
        {
            float a0 = 0.25f * (he[(4 * w) * 33] + he[(4 * w + 1) * 33] +
                                he[(4 * w + 2) * 33] + he[(4 * w + 3) * 33]);
            tmp[0] = a0;
            mk2 = -a0 * a0;
        }
#pragma unroll
        for (int c = 1; c < 33; c++) {
            float a = 0.25f * (he[(4 * w) * 33 + c] + he[(4 * w + 1) * 33 + c] +
                               he[(4 * w + 2) * 33 + c] + he[(4 * w + 3) * 33 + c]);
            tmp[c] = a;
            mk2 += a * a;
        }
        float dd = sqrtf(fmaxf(fabsf(mk2), 1e-8f));
#pragma unroll
        for (int c = 0; c < 33; c++) hp[w * 33 + c] = tmp[c] / dd;
    }
    __syncthreads();
    float ssq = 0.f, sdz = 0.f, zz = 0.f;
    for (int j = w; j < 512; j += 64) {
        float val = hp[(j >> 5) * 33 + 1 + (j & 31)];
        float zv = mlr_z[j];
        ssq += val * val;
        sdz += val * zv;
        zz += zv * zv;
        out[128 + b * 513 + 1 + j] = val;
    }
#pragma unroll
    for (int off = 32; off > 0; off >>= 1) {
        ssq += __shfl_down(ssq, off);
        sdz += __shfl_down(sdz, off);
        zz += __shfl_down(zz, off);
    }
    if (w == 0) {
        float nz = sqrtf(zz);
        float a = mlr_a[0];
        float cha = coshf(a);
        float wt = sinhf(a) * nz;
        float cn = cha * nz;
        float bet = sqrtf(fmaxf(cn * cn - wt * wt, 1e-8f));
        float ft = sqrtf(1.f + ssq);
        float alpha = -wt * ft + cha * sdz;
        out[128 + b * 513] = ft;
        out[b] = bet * asinhf(alpha / bet);
    }
}

extern "C" void kernel_launch(void* const* d_in, const int* in_sizes, int n_in,
                              void* d_out, int out_size, void* d_ws, size_t ws_size,
                              hipStream_t stream) {
    const float* x       = (const float*)d_in[0];
    const int*   domains = (const int*)d_in[1];
    const float* conv1_w = (const float*)d_in[2];
    const float* bn1_w   = (const float*)d_in[3];
    const float* bn1_b   = (const float*)d_in[4];
    const float* dw_w    = (const float*)d_in[5];
    const float* bn2_w   = (const float*)d_in[6];
    const float* bn2_b   = (const float*)d_in[7];
    const float* ec1_w   = (const float*)d_in[8];
    const float* b2c1_w  = (const float*)d_in[9];
    const float* b2c2_w  = (const float*)d_in[10];
    const float* bn3_w   = (const float*)d_in[11];
    const float* bn3_b   = (const float*)d_in[12];
    const float* lc1_w   = (const float*)d_in[13];
    const float* bn_beta = (const float*)d_in[14];
    const float* bn_gamma= (const float*)d_in[15];
    const float* mlr_a   = (const float*)d_in[16];
    const float* mlr_z   = (const float*)d_in[17];
    float* out = (float*)d_out;
    float* ws  = (float*)d_ws;

    hipMemsetAsync(ws, 0, ZERO_N * sizeof(float), stream);
    k_corr<<<256, 256, 0, stream>>>(x, ws);
    k_fold<<<1, 512, 0, stream>>>(conv1_w, bn1_w, bn1_b, ws);
    k_dw<<<dim3(128, 4), 256, 0, stream>>>(x, conv1_w, dw_w, ws);
    k_pool2<<<(128 * 32 * 256) / 256, 256, 0, stream>>>(bn2_w, bn2_b, ws);
    k_sep<<<Bn, 256, 0, stream>>>(ec1_w, b2c1_w, b2c2_w, ws);
    k_head<<<Bn, 256, 0, stream>>>(bn3_w, bn3_b, lc1_w, domains, ws);
    k_mu<<<1, 64, 0, stream>>>(ws);
    k_tangent<<<Bn, 64, 0, stream>>>(domains, ws);
    k_final<<<Bn, 64, 0, stream>>>(domains, bn_beta, bn_gamma, mlr_a, mlr_z, ws, out);
}

// Round 3
// 305.614 us; speedup vs baseline: 2.4589x; 1.2086x over previous
//
#include <hip/hip_runtime.h>
#include <math.h>

#define Bn 128
#define Hh 32
#define Wx 1024
#define WP 1056
#define W1O 1025

#define N1f 4198400.0f   // 128*32*1025
#define N2f 131200.0f    // 128*1025
#define N3f 33024.0f     // 128*258

// ---- ws float offsets ----
#define OFF_C      0     // 32  autocorr C[d]
#define OFF_S      32    // 1   total sum of x
#define OFF_EH     33    // 15  E[j] head j=0..14
#define OFF_ET     48    // 15  E[1009+j]
#define OFF_G      64    // 480 G[d*15+j], j head
#define OFF_G2     544   // 480 G2[d*15+j], j tail
#define OFF_A1     1024  // 16
#define OFF_B1     1040  // 16
#define OFF_S1_2   1056  // 32
#define OFF_S2_2   1088  // 32
#define OFF_S1_3   1120  // 32
#define OFF_S2_3   1152  // 32
#define OFF_SEG    1184  // 132
#define OFF_CNT    1316  // 4
#define OFF_MU     1320  // 132
#define OFF_DSQ    1452  // 4
#define ZERO_N     1456
#define OFF_DWOUT  2048                      // 128*32*1025 = 4198400
#define OFF_POOLED (2048 + 4198400)          // 128*32*256  = 1048576
// DWOUT region is dead after k_pool2 -> overlay later tensors there
#define OFF_C3     OFF_DWOUT                 // 128*32*258 = 1056768
#define OFF_PTS    (OFF_C3 + 1056768)        // 128*64*33  = 270336
#define OFF_VO     (OFF_PTS + 270336)        // 128*64*33  = 270336

__device__ __forceinline__ float eluf(float x) { return x > 0.f ? x : expm1f(x); }

// ---------------- K1: lag-autocorrelation statistics of x ----------------
__global__ __launch_bounds__(256, 1) void k_corr(const float* __restrict__ x,
                                                 float* __restrict__ ws) {
    __shared__ float xs[1060];
    __shared__ float cacc[32];
    __shared__ float gacc[480];
    __shared__ float g2acc[480];
    __shared__ float eacc[30];
    int tid = threadIdx.x;
    for (int i = tid; i < 480; i += 256) { gacc[i] = 0.f; g2acc[i] = 0.f; }
    if (tid < 32) cacc[tid] = 0.f;
    if (tid < 30) eacc[tid] = 0.f;
    for (int i = 1024 + tid; i < 1060; i += 256) xs[i] = 0.f;
    float acc[32];
#pragma unroll
    for (int d = 0; d < 32; d++) acc[d] = 0.f;
    float sp = 0.f;
    int r0 = blockIdx.x * 16;
    for (int rr = 0; rr < 16; rr++) {
        __syncthreads();
        const float4* xr = (const float4*)(x + (r0 + rr) * Wx);
        ((float4*)xs)[tid] = xr[tid];
        __syncthreads();
        float v[36];
#pragma unroll
        for (int q = 0; q < 9; q++) {
            float4 t4 = ((const float4*)xs)[tid + q];
            v[4 * q] = t4.x; v[4 * q + 1] = t4.y; v[4 * q + 2] = t4.z; v[4 * q + 3] = t4.w;
        }
#pragma unroll
        for (int i = 0; i < 4; i++) {
            sp += v[i];
#pragma unroll
            for (int d = 0; d < 32; d++) acc[d] += v[i] * v[i + d];
        }
        if (tid < 240) {
#pragma unroll
            for (int q = 0; q < 2; q++) {
                int idx = tid * 2 + q;
                int d = idx / 15, j = idx - d * 15;
                gacc[idx]  += xs[j] * xs[j + d];
                g2acc[idx] += xs[1009 + j] * xs[1009 + j + d];
            }
        } else if (tid < 270) {
            int j = tid - 240;
            eacc[j] += (j < 15) ? xs[j] : xs[1009 + (j - 15)];
        }
    }
    int lane = tid & 63;
#pragma unroll
    for (int d = 0; d < 32; d++) {
        float vv = acc[d];
#pragma unroll
        for (int off = 32; off > 0; off >>= 1) vv += __shfl_down(vv, off);
        if (lane == 0) atomicAdd(&cacc[d], vv);
    }
    {
        float vv = sp;
#pragma unroll
        for (int off = 32; off > 0; off >>= 1) vv += __shfl_down(vv, off);
        if (lane == 0) atomicAdd(&ws[OFF_S], vv);
    }
    __syncthreads();
    if (tid < 32) atomicAdd(&ws[OFF_C + tid], cacc[tid]);
    for (int i = tid; i < 480; i += 256) {
        atomicAdd(&ws[OFF_G + i], gacc[i]);
        atomicAdd(&ws[OFF_G2 + i], g2acc[i]);
    }
    if (tid < 30) atomicAdd(&ws[OFF_EH + tid], eacc[tid]);
}

// ---------------- K1b: assemble BN1 mean/var from correlations ----------------
__global__ __launch_bounds__(512) void k_fold(const float* __restrict__ w1,
                                              const float* __restrict__ bn1w,
                                              const float* __restrict__ bn1b,
                                              float* __restrict__ ws) {
    __shared__ float PH[32][16];
    __shared__ float PT[32][16];
    __shared__ float Ts[32];
    __shared__ float w1s[512];
    __shared__ float sumsq[16];
    __shared__ float meanv[16];
    int tid = threadIdx.x;
    w1s[tid] = w1[tid];
    if (tid < 16) sumsq[tid] = 0.f;
    if (tid < 32) {
        int d = tid;
        float s = 0.f;
        for (int j = 0; j < 15; j++) { s += ws[OFF_G + d * 15 + j]; PH[d][j] = s; }
        float s2 = 0.f;
        for (int j = 14; j >= 0; j--) { s2 += ws[OFF_G2 + d * 15 + j]; PT[d][j] = s2; }
    } else if (tid >= 64 && tid < 96) {
        int k = tid - 64;
        float t = ws[OFF_S];
        for (int j = 0; j <= k - 17; j++) t -= ws[OFF_EH + j];
        if (k <= 14) for (int j = k; j < 15; j++) t -= ws[OFF_ET + j];
        Ts[k] = t;
    }
    __syncthreads();
    int c = tid >> 5, d = tid & 31;
    float Cd = ws[OFF_C + d];
    float part = 0.f;
    for (int k = 0; k + d < 32; k++) {
        float head = (k >= 17) ? PH[d][k - 17] : 0.f;
        float tail = (k <= 14) ? PT[d][k] : 0.f;
        float R = Cd - head - tail;
        part += w1s[c * 32 + k] * w1s[c * 32 + k + d] * R;
    }
    if (d > 0) part *= 2.f;
    atomicAdd(&sumsq[c], part);
    if (d == 0) {
        float mp = 0.f;
        for (int k = 0; k < 32; k++) mp += w1s[c * 32 + k] * Ts[k];
        meanv[c] = mp / N1f;
    }
    __syncthreads();
    if (tid < 16) {
        float mean = meanv[tid];
        float var = fmaxf(sumsq[tid] / N1f - mean * mean, 0.f);
        float a = bn1w[tid] / sqrtf(var + 1e-3f);
        ws[OFF_A1 + tid] = a;
        ws[OFF_B1 + tid] = bn1b[tid] - mean * a;
    }
}

// ---------------- K2: fused conv1+bn1+dw-conv via Y-fold, plus BN2 stats ----------------
__global__ __launch_bounds__(256) void k_dw(const float* __restrict__ x,
                                            const float* __restrict__ w1,
                                            const float* __restrict__ dww,
                                            float* __restrict__ ws) {
    __shared__ float dws[256];
    __shared__ float w1s[128];
    __shared__ float Dv[8];
    __shared__ float a1s[4], b1s[4];
    __shared__ float Ys[8 * WP];
    __shared__ float st[16];
    int tid = threadIdx.x;
    int b = blockIdx.x;
    int ocb = blockIdx.y * 8;
    int g0 = ocb >> 1;
    dws[tid] = dww[ocb * 32 + tid];
    if (tid < 128) w1s[tid] = w1[g0 * 32 + tid];
    if (tid < 16) st[tid] = 0.f;
    if (tid < 4) { a1s[tid] = ws[OFF_A1 + g0 + tid]; b1s[tid] = ws[OFF_B1 + g0 + tid]; }
    __syncthreads();
    if (tid < 8) {
        float d = 0.f;
        for (int h = 0; h < 32; h++) d += dws[tid * 32 + h];
        Dv[tid] = d;
    }
    for (int p = tid; p < WP; p += 256) {
        float acc[8];
#pragma unroll
        for (int j = 0; j < 8; j++) acc[j] = 0.f;
        bool inr = (p >= 16 && p < 16 + Wx);
        const float* xb = x + b * (Hh * Wx) + (p - 16);
        for (int h = 0; h < Hh; h++) {
            float xv = inr ? xb[h * Wx] : 0.f;
#pragma unroll
            for (int j = 0; j < 8; j++) acc[j] += xv * dws[j * 32 + h];
        }
#pragma unroll
        for (int j = 0; j < 8; j++) Ys[j * WP + p] = acc[j];
    }
    __syncthreads();
    float* dwout = ws + OFF_DWOUT;
    int lane = tid & 63;
    for (int j = 0; j < 8; j++) {
        int oc = ocb + j;
        int gl = j >> 1;
        float a = a1s[gl], bb = b1s[gl] * Dv[j];
        float ls1 = 0.f, ls2 = 0.f;
        for (int w = tid; w < W1O; w += 256) {
            float s = 0.f;
#pragma unroll 8
            for (int k = 0; k < 32; k++) s += w1s[gl * 32 + k] * Ys[j * WP + w + k];
            float val = a * s + bb;
            dwout[(b * 32 + oc) * W1O + w] = val;
            ls1 += val; ls2 += val * val;
        }
#pragma unroll
        for (int off = 32; off > 0; off >>= 1) {
            ls1 += __shfl_down(ls1, off);
            ls2 += __shfl_down(ls2, off);
        }
        if (lane == 0) { atomicAdd(&st[j], ls1); atomicAdd(&st[8 + j], ls2); }
    }
    __syncthreads();
    if (tid < 8) atomicAdd(&ws[OFF_S1_2 + ocb + tid], st[tid]);
    else if (tid < 16) atomicAdd(&ws[OFF_S2_2 + ocb + tid - 8], st[tid]);
}

// ---------------- K3: BN2 apply + ELU + avgpool4 ----------------
__global__ __launch_bounds__(256) void k_pool2(const float* __restrict__ bn2w,
                                               const float* __restrict__ bn2b,
                                               float* __restrict__ ws) {
    int idx = blockIdx.x * 256 + threadIdx.x;
    if (idx >= 128 * 32 * 256) return;
    int b = idx >> 13;
    int r = idx & 8191;
    int c = r >> 8;
    int wp = r & 255;
    float mean = ws[OFF_S1_2 + c] / N2f;
    float var = fmaxf(ws[OFF_S2_2 + c] / N2f - mean * mean, 0.f);
    float a = bn2w[c] / sqrtf(var + 1e-3f);
    float bb = bn2b[c] - mean * a;
    const float* dwo = ws + OFF_DWOUT + (b * 32 + c) * W1O + wp * 4;
    float acc = 0.f;
#pragma unroll
    for (int j = 0; j < 4; j++) {
        float e = a * dwo[j] + bb;
        acc += eluf(e);
    }
    ws[OFF_POOLED + idx] = 0.25f * acc;
}

// ---------------- K4: ec1 + b2c1 + b2c2 + BN3 stats ----------------
__global__ __launch_bounds__(256) void k_sep(const float* __restrict__ ec1w,
                                             const float* __restrict__ bc1w,
                                             const float* __restrict__ bc2w,
                                             float* __restrict__ ws) {
    __shared__ float e2s[32 * 258];
    __shared__ float insP[4][272];
    __shared__ float e1P[4][288];
    __shared__ float ec1s[512], bc1s[512], bc2s[1024];
    __shared__ float st[64];
    int tid = threadIdx.x;
    int b = blockIdx.x;
    int wave = tid >> 6, lane = tid & 63;
    for (int i = tid; i < 512; i += 256) { ec1s[i] = ec1w[i]; bc1s[i] = bc1w[i]; }
    for (int i = tid; i < 1024; i += 256) bc2s[i] = bc2w[i];
    if (tid < 64) st[tid] = 0.f;
    for (int i = lane; i < 272; i += 64) insP[wave][i] = 0.f;
    for (int i = lane; i < 288; i += 64) e1P[wave][i] = 0.f;
    __syncthreads();
    const float* pooled = ws + OFF_POOLED + b * 8192;
    for (int it = 0; it < 8; it++) {
        int c = it * 4 + wave;
        for (int i = lane; i < 256; i += 64) insP[wave][8 + i] = pooled[c * 256 + i];
        __syncthreads();
        for (int w = lane; w < 257; w += 64) {
            float s = 0.f;
#pragma unroll
            for (int k = 0; k < 16; k++) s += insP[wave][w + k] * ec1s[c * 16 + k];
            e1P[wave][8 + w] = s;
        }
        __syncthreads();
        for (int w = lane; w < 258; w += 64) {
            float s = 0.f;
#pragma unroll
            for (int k = 0; k < 16; k++) s += e1P[wave][w + k] * bc1s[c * 16 + k];
            e2s[c * 258 + w] = s;
        }
        __syncthreads();
    }
    float* c3 = ws + OFF_C3 + b * 8256;
    for (int idx = tid; idx < 8256; idx += 256) {
        int o = idx / 258;
        int w = idx - o * 258;
        float s = 0.f;
#pragma unroll 8
        for (int cc = 0; cc < 32; cc++) s += e2s[cc * 258 + w] * bc2s[o * 32 + cc];
        c3[idx] = s;
        atomicAdd(&st[o], s);
        atomicAdd(&st[32 + o], s * s);
    }
    __syncthreads();
    if (tid < 64) atomicAdd(&ws[OFF_S1_3 + tid], st[tid]);
}

// ---------------- K5: BN3+ELU+pool4 + normalize + lift + lc1 (o=1..32) -> pts ----------------
// 4 subs x 64 w threads; o=0 row of lc1 output is discarded by the reference.
__global__ __launch_bounds__(256, 1) void k_head(const float* __restrict__ bn3w,
                                                 const float* __restrict__ bn3b,
                                                 const float* __restrict__ lc1w,
                                                 const int* __restrict__ domains,
                                                 float* __restrict__ ws) {
    __shared__ float q[2048];        // [c][w] 32x64
    __shared__ float lc1s[1089];
    __shared__ float psum[33];
    __shared__ float ssyp[4][64];
    __shared__ float a3s[32], b3s[32];
    int tid = threadIdx.x;
    int b = blockIdx.x;
    if (tid < 32) {
        float mean = ws[OFF_S1_3 + tid] / N3f;
        float var = fmaxf(ws[OFF_S2_3 + tid] / N3f - mean * mean, 0.f);
        float a = bn3w[tid] / sqrtf(var + 1e-3f);
        a3s[tid] = a;
        b3s[tid] = bn3b[tid] - mean * a;
    }
    for (int i = tid; i < 1089; i += 256) lc1s[i] = lc1w[i];
    __syncthreads();
    const float* c3 = ws + OFF_C3 + b * 8256;
    for (int idx = tid; idx < 2048; idx += 256) {
        int c = idx >> 6, wp = idx & 63;
        float a = a3s[c], bb = b3s[c];
        float acc = 0.f;
#pragma unroll
        for (int j = 0; j < 4; j++) {
            float e = a * c3[c * 258 + wp * 4 + j] + bb;
            acc += eluf(e);
        }
        q[idx] = 0.25f * acc;
    }
    __syncthreads();
    int w = tid & 63, sub = tid >> 6;
    float qv[32];
    float ssq = 0.f;
#pragma unroll
    for (int c = 0; c < 32; c++) { qv[c] = q[c * 64 + w]; ssq += qv[c] * qv[c]; }
    float inv = 1.f / fmaxf(sqrtf(ssq), 1e-12f);
    float ss2 = 0.f;
#pragma unroll
    for (int c = 0; c < 32; c++) { qv[c] *= inv; ss2 += qv[c] * qv[c]; }
    float t = sqrtf(1.f + ss2);
    int o0 = 1 + sub * 8;
    float p[8];
    float ssy_part = 0.f;
#pragma unroll
    for (int i = 0; i < 8; i++) {
        int o = o0 + i;
        float s = lc1s[o * 33] * t;
#pragma unroll
        for (int c = 0; c < 32; c++) s += lc1s[o * 33 + 1 + c] * qv[c];
        p[i] = s;
        ssy_part += s * s;
    }
    ssyp[sub][w] = ssy_part;
    float* pr = ws + OFF_PTS + (b * 64 + w) * 33;
#pragma unroll
    for (int i = 0; i < 8; i++) pr[o0 + i] = p[i];
    __syncthreads();
    float yt = 0.f;
    if (sub == 0) {
        float ssy = ssyp[0][w] + ssyp[1][w] + ssyp[2][w] + ssyp[3][w];
        yt = sqrtf(1.f + ssy);
        pr[0] = yt;
    }
    // wave-level reductions over w (lane index == w within each wave)
#pragma unroll
    for (int i = 0; i < 8; i++) {
        float vv = p[i];
#pragma unroll
        for (int off = 32; off > 0; off >>= 1) vv += __shfl_down(vv, off);
        if (w == 0) psum[o0 + i] = vv;
    }
    {
        float vv = yt;  // nonzero only in sub==0 wave; other waves write nothing
#pragma unroll
        for (int off = 32; off > 0; off >>= 1) vv += __shfl_down(vv, off);
        if (w == 0 && sub == 0) psum[0] = vv;
    }
    __syncthreads();
    int dom = domains[b];
    if (tid < 33) atomicAdd(&ws[OFF_SEG + dom * 33 + tid], psum[tid]);
    if (tid == 64) atomicAdd(&ws[OFF_CNT + dom], 64.f);
}

// ---------------- K6: per-domain mean mu ----------------
__global__ void k_mu(float* __restrict__ ws) {
    int d = threadIdx.x;
    if (d < 4) {
        float cnt = fmaxf(ws[OFF_CNT + d], 1.f);
        float sv[33];
        float s0 = ws[OFF_SEG + d * 33] / cnt;
        sv[0] = s0;
        float sum = 0.f;
        for (int c = 1; c < 33; c++) {
            sv[c] = ws[OFF_SEG + d * 33 + c] / cnt;
            sum += sv[c] * sv[c];
        }
        float mk = -s0 * s0 + sum;
        float dn = sqrtf(fmaxf(fabsf(mk), 1e-8f));
        for (int c = 0; c < 33; c++) ws[OFF_MU + d * 33 + c] = sv[c] / dn;
    }
}

// ---------------- K7: log-map at mu, transport to origin, dist^2 sums ----------------
__global__ __launch_bounds__(64, 1) void k_tangent(const int* __restrict__ domains,
                                                   float* __restrict__ ws) {
    int b = blockIdx.x;
    int w = threadIdx.x;
    int dom = domains[b];
    const float* mu = ws + OFF_MU + dom * 33;
    const float* pr = ws + OFF_PTS + (b * 64 + w) * 33;
    float m[33], p[33];
#pragma unroll
    for (int c = 0; c < 33; c++) { m[c] = mu[c]; p[c] = pr[c]; }
    float ip = -m[0] * p[0];
#pragma unroll
    for (int c = 1; c < 33; c++) ip += m[c] * p[c];
    float z = fmaxf(-ip, 1.f + 1e-7f);
    float dist = acoshf(z);
    float u[33];
#pragma unroll
    for (int c = 0; c < 33; c++) u[c] = p[c] + ip * m[c];
    float mk = -u[0] * u[0];
#pragma unroll
    for (int c = 1; c < 33; c++) mk += u[c] * u[c];
    float un = sqrtf(fmaxf(mk, 1e-8f));
    float r = dist / un;
    float v0 = r * u[0];
    float coef = -v0 / (1.f + m[0]);
    float* vo = ws + OFF_VO + (b * 64 + w) * 33;
    vo[0] = v0 + coef * (m[0] + 1.f);
#pragma unroll
    for (int c = 1; c < 33; c++) vo[c] = r * u[c] + coef * m[c];
    float dsq = dist * dist;
#pragma unroll
    for (int off = 32; off > 0; off >>= 1) dsq += __shfl_down(dsq, off);
    if (w == 0) atomicAdd(&ws[OFF_DSQ + dom], dsq);
}

// ---------------- K8: scale, transport to beta, expmap, L-ELU, L-pool, MLR ----------------
__global__ __launch_bounds__(64, 1) void k_final(const int* __restrict__ domains,
                                                 const float* __restrict__ beta,
                                                 const float* __restrict__ gamma,
                                                 const float* __restrict__ mlr_a,
                                                 const float* __restrict__ mlr_z,
                                                 float* __restrict__ ws,
                                                 float* __restrict__ out) {
    __shared__ float he[64 * 33];
    __shared__ float hp[16 * 33];
    int b = blockIdx.x;
    int w = threadIdx.x;
    int dom = domains[b];
    float cnt = fmaxf(ws[OFF_CNT + dom], 1.f);
    float var = ws[OFF_DSQ + dom] / cnt;
    float sc = gamma[0] / sqrtf(var + 1e-5f);
    float bt[33];
#pragma unroll
    for (int c = 0; c < 33; c++) bt[c] = beta[c];
    const float* vo = ws + OFF_VO + (b * 64 + w) * 33;
    float v[33];
#pragma unroll
    for (int c = 0; c < 33; c++) v[c] = vo[c] * sc;
    float mb = -bt[0] * v[0];
#pragma unroll
    for (int c = 1; c < 33; c++) mb += bt[c] * v[c];
    float coef = mb / (1.f + bt[0]);
    v[0] += coef * (1.f + bt[0]);
#pragma unroll
    for (int c = 1; c < 33; c++) v[c] += coef * bt[c];
    float mk = -v[0] * v[0];
#pragma unroll
    for (int c = 1; c < 33; c++) mk += v[c] * v[c];
    float vn = sqrtf(fmaxf(mk, 1e-8f));
    float ch = coshf(vn), sh = sinhf(vn) / vn;
    float ss = 0.f;
#pragma unroll
    for (int c = 1; c < 33; c++) {
        float y = ch * bt[c] + sh * v[c];
        float s = eluf(y);
        he[w * 33 + c] = s;
        ss += s * s;
    }
    he[w * 33] = sqrtf(1.f + ss);
    __syncthreads();
    if (w < 16) {
        float tmp[33];
        float mk2;
        {
            float a0 = 0.25f * (he[(4 * w) * 33] + he[(4 * w + 1) * 33] +
                                he[(4 * w + 2) * 33] + he[(4 * w + 3) * 33]);
            tmp[0] = a0;
            mk2 = -a0 * a0;
        }
#pragma unroll
        for (int c = 1; c < 33; c++) {
            float a = 0.25f * (he[(4 * w) * 33 + c] + he[(4 * w + 1) * 33 + c] +
                               he[(4 * w + 2) * 33 + c] + he[(4 * w + 3) * 33 + c]);
            tmp[c] = a;
            mk2 += a * a;
        }
        float dd = sqrtf(fmaxf(fabsf(mk2), 1e-8f));
#pragma unroll
        for (int c = 0; c < 33; c++) hp[w * 33 + c] = tmp[c] / dd;
    }
    __syncthreads();
    float ssq = 0.f, sdz = 0.f, zz = 0.f;
    for (int j = w; j < 512; j += 64) {
        float val = hp[(j >> 5) * 33 + 1 + (j & 31)];
        float zv = mlr_z[j];
        ssq += val * val;
        sdz += val * zv;
        zz += zv * zv;
        out[128 + b * 513 + 1 + j] = val;
    }
#pragma unroll
    for (int off = 32; off > 0; off >>= 1) {
        ssq += __shfl_down(ssq, off);
        sdz += __shfl_down(sdz, off);
        zz += __shfl_down(zz, off);
    }
    if (w == 0) {
        float nz = sqrtf(zz);
        float a = mlr_a[0];
        float cha = coshf(a);
        float wt = sinhf(a) * nz;
        float cn = cha * nz;
        float bet = sqrtf(fmaxf(cn * cn - wt * wt, 1e-8f));
        float ft = sqrtf(1.f + ssq);
        float alpha = -wt * ft + cha * sdz;
        out[128 + b * 513] = ft;
        out[b] = bet * asinhf(alpha / bet);
    }
}

extern "C" void kernel_launch(void* const* d_in, const int* in_sizes, int n_in,
                              void* d_out, int out_size, void* d_ws, size_t ws_size,
                              hipStream_t stream) {
    const float* x       = (const float*)d_in[0];
    const int*   domains = (const int*)d_in[1];
    const float* conv1_w = (const float*)d_in[2];
    const float* bn1_w   = (const float*)d_in[3];
    const float* bn1_b   = (const float*)d_in[4];
    const float* dw_w    = (const float*)d_in[5];
    const float* bn2_w   = (const float*)d_in[6];
    const float* bn2_b   = (const float*)d_in[7];
    const float* ec1_w   = (const float*)d_in[8];
    const float* b2c1_w  = (const float*)d_in[9];
    const float* b2c2_w  = (const float*)d_in[10];
    const float* bn3_w   = (const float*)d_in[11];
    const float* bn3_b   = (const float*)d_in[12];
    const float* lc1_w   = (const float*)d_in[13];
    const float* bn_beta = (const float*)d_in[14];
    const float* bn_gamma= (const float*)d_in[15];
    const float* mlr_a   = (const float*)d_in[16];
    const float* mlr_z   = (const float*)d_in[17];
    float* out = (float*)d_out;
    float* ws  = (float*)d_ws;

    hipMemsetAsync(ws, 0, ZERO_N * sizeof(float), stream);
    k_corr<<<256, 256, 0, stream>>>(x, ws);
    k_fold<<<1, 512, 0, stream>>>(conv1_w, bn1_w, bn1_b, ws);
    k_dw<<<dim3(128, 4), 256, 0, stream>>>(x, conv1_w, dw_w, ws);
    k_pool2<<<(128 * 32 * 256) / 256, 256, 0, stream>>>(bn2_w, bn2_b, ws);
    k_sep<<<Bn, 256, 0, stream>>>(ec1_w, b2c1_w, b2c2_w, ws);
    k_head<<<Bn, 256, 0, stream>>>(bn3_w, bn3_b, lc1_w, domains, ws);
    k_mu<<<1, 64, 0, stream>>>(ws);
    k_tangent<<<Bn, 64, 0, stream>>>(domains, ws);
    k_final<<<Bn, 64, 0, stream>>>(domains, bn_beta, bn_gamma, mlr_a, mlr_z, ws, out);
}

// Round 4
// 244.977 us; speedup vs baseline: 3.0675x; 1.2475x over previous
//
#include <hip/hip_runtime.h>
#include <math.h>

#define Bn 128
#define Hh 32
#define Wx 1024
#define WP 1056

#define N1f 4198400.0f   // 128*32*1025
#define N2f 131200.0f    // 128*1025
#define N3f 33024.0f     // 128*258

// ---- ws float offsets ----
#define OFF_C      0     // 32  autocorr C[d]
#define OFF_S      32    // 1   total sum of x
#define OFF_EH     33    // 15
#define OFF_ET     48    // 15
#define OFF_G      64    // 480
#define OFF_G2     544   // 480
#define OFF_A1     1024  // 16
#define OFF_B1     1040  // 16
#define OFF_S1_2   1056  // 32
#define OFF_S2_2   1088  // 32
#define OFF_S1_3   1120  // 32
#define OFF_S2_3   1152  // 32
#define OFF_SEG    1184  // 132
#define OFF_CNT    1316  // 4
#define OFF_MU     1320  // 132
#define OFF_DSQ    1452  // 4
#define ZERO_N     1456
#define OFF_DWOUT  2048                      // 128*32*1024 = 4194304 (stride 1024; w=1024 tail stats-only)
#define OFF_E2     (2048 + 4194304)          // 128*32*258 = 1056768
// DWOUT region dead after k_pe -> overlay later tensors there
#define OFF_C3     OFF_DWOUT                 // 128*32*258 = 1056768
#define OFF_PTS    (OFF_C3 + 1056768)        // 128*64*33  = 270336
#define OFF_VO     (OFF_PTS + 270336)        // 128*64*33  = 270336

__device__ __forceinline__ float eluf(float x) { return x > 0.f ? x : expm1f(x); }

// ---------------- K1: lag-autocorrelation statistics of x ----------------
__global__ __launch_bounds__(256, 1) void k_corr(const float* __restrict__ x,
                                                 float* __restrict__ ws) {
    __shared__ float xs[1060];
    __shared__ float cacc[32];
    __shared__ float gacc[480];
    __shared__ float g2acc[480];
    __shared__ float eacc[30];
    int tid = threadIdx.x;
    for (int i = tid; i < 480; i += 256) { gacc[i] = 0.f; g2acc[i] = 0.f; }
    if (tid < 32) cacc[tid] = 0.f;
    if (tid < 30) eacc[tid] = 0.f;
    for (int i = 1024 + tid; i < 1060; i += 256) xs[i] = 0.f;
    float acc[32];
#pragma unroll
    for (int d = 0; d < 32; d++) acc[d] = 0.f;
    float sp = 0.f;
    int r0 = blockIdx.x * 16;
    for (int rr = 0; rr < 16; rr++) {
        __syncthreads();
        const float4* xr = (const float4*)(x + (r0 + rr) * Wx);
        ((float4*)xs)[tid] = xr[tid];
        __syncthreads();
        float v[36];
#pragma unroll
        for (int q = 0; q < 9; q++) {
            float4 t4 = ((const float4*)xs)[tid + q];
            v[4 * q] = t4.x; v[4 * q + 1] = t4.y; v[4 * q + 2] = t4.z; v[4 * q + 3] = t4.w;
        }
#pragma unroll
        for (int i = 0; i < 4; i++) {
            sp += v[i];
#pragma unroll
            for (int d = 0; d < 32; d++) acc[d] += v[i] * v[i + d];
        }
        if (tid < 240) {
#pragma unroll
            for (int q = 0; q < 2; q++) {
                int idx = tid * 2 + q;
                int d = idx / 15, j = idx - d * 15;
                gacc[idx]  += xs[j] * xs[j + d];
                g2acc[idx] += xs[1009 + j] * xs[1009 + j + d];
            }
        } else if (tid < 270) {
            int j = tid - 240;
            eacc[j] += (j < 15) ? xs[j] : xs[1009 + (j - 15)];
        }
    }
    int lane = tid & 63;
#pragma unroll
    for (int d = 0; d < 32; d++) {
        float vv = acc[d];
#pragma unroll
        for (int off = 32; off > 0; off >>= 1) vv += __shfl_down(vv, off);
        if (lane == 0) atomicAdd(&cacc[d], vv);
    }
    {
        float vv = sp;
#pragma unroll
        for (int off = 32; off > 0; off >>= 1) vv += __shfl_down(vv, off);
        if (lane == 0) atomicAdd(&ws[OFF_S], vv);
    }
    __syncthreads();
    if (tid < 32) atomicAdd(&ws[OFF_C + tid], cacc[tid]);
    for (int i = tid; i < 480; i += 256) {
        atomicAdd(&ws[OFF_G + i], gacc[i]);
        atomicAdd(&ws[OFF_G2 + i], g2acc[i]);
    }
    if (tid < 30) atomicAdd(&ws[OFF_EH + tid], eacc[tid]);
}

// ---------------- K1b: assemble BN1 mean/var from correlations ----------------
__global__ __launch_bounds__(512) void k_fold(const float* __restrict__ w1,
                                              const float* __restrict__ bn1w,
                                              const float* __restrict__ bn1b,
                                              float* __restrict__ ws) {
    __shared__ float PH[32][16];
    __shared__ float PT[32][16];
    __shared__ float Ts[32];
    __shared__ float w1s[512];
    __shared__ float sumsq[16];
    __shared__ float meanv[16];
    int tid = threadIdx.x;
    w1s[tid] = w1[tid];
    if (tid < 16) sumsq[tid] = 0.f;
    if (tid < 32) {
        int d = tid;
        float s = 0.f;
        for (int j = 0; j < 15; j++) { s += ws[OFF_G + d * 15 + j]; PH[d][j] = s; }
        float s2 = 0.f;
        for (int j = 14; j >= 0; j--) { s2 += ws[OFF_G2 + d * 15 + j]; PT[d][j] = s2; }
    } else if (tid >= 64 && tid < 96) {
        int k = tid - 64;
        float t = ws[OFF_S];
        for (int j = 0; j <= k - 17; j++) t -= ws[OFF_EH + j];
        if (k <= 14) for (int j = k; j < 15; j++) t -= ws[OFF_ET + j];
        Ts[k] = t;
    }
    __syncthreads();
    int c = tid >> 5, d = tid & 31;
    float Cd = ws[OFF_C + d];
    float part = 0.f;
    for (int k = 0; k + d < 32; k++) {
        float head = (k >= 17) ? PH[d][k - 17] : 0.f;
        float tail = (k <= 14) ? PT[d][k] : 0.f;
        float R = Cd - head - tail;
        part += w1s[c * 32 + k] * w1s[c * 32 + k + d] * R;
    }
    if (d > 0) part *= 2.f;
    atomicAdd(&sumsq[c], part);
    if (d == 0) {
        float mp = 0.f;
        for (int k = 0; k < 32; k++) mp += w1s[c * 32 + k] * Ts[k];
        meanv[c] = mp / N1f;
    }
    __syncthreads();
    if (tid < 16) {
        float mean = meanv[tid];
        float var = fmaxf(sumsq[tid] / N1f - mean * mean, 0.f);
        float a = bn1w[tid] / sqrtf(var + 1e-3f);
        ws[OFF_A1 + tid] = a;
        ws[OFF_B1 + tid] = bn1b[tid] - mean * a;
    }
}

// ---------------- K2: fused conv1+bn1+dw-conv via Y-fold, plus BN2 stats ----------------
// grid (128, 4): batch b, output channels [8*y, 8*y+8)
__global__ __launch_bounds__(256) void k_dw(const float* __restrict__ x,
                                            const float* __restrict__ w1,
                                            const float* __restrict__ dww,
                                            float* __restrict__ ws) {
    __shared__ float dws[256];
    __shared__ float w1s[128];
    __shared__ float Dv[8];
    __shared__ float a1s[4], b1s[4];
    __shared__ float Ys[8 * WP];
    __shared__ float st[16];
    int tid = threadIdx.x;
    int b = blockIdx.x;
    int ocb = blockIdx.y * 8;
    int g0 = ocb >> 1;
    dws[tid] = dww[ocb * 32 + tid];
    if (tid < 128) w1s[tid] = w1[g0 * 32 + tid];
    if (tid < 16) st[tid] = 0.f;
    if (tid < 4) { a1s[tid] = ws[OFF_A1 + g0 + tid]; b1s[tid] = ws[OFF_B1 + g0 + tid]; }
    __syncthreads();
    if (tid < 8) {
        float d = 0.f;
        for (int h = 0; h < 32; h++) d += dws[tid * 32 + h];
        Dv[tid] = d;
    }
    // Phase A: Y(j,p) = sum_h xpad(b,h,p) * dw[ocb+j,h]
    for (int p = tid; p < WP; p += 256) {
        float acc[8];
#pragma unroll
        for (int j = 0; j < 8; j++) acc[j] = 0.f;
        bool inr = (p >= 16 && p < 16 + Wx);
        const float* xb = x + b * (Hh * Wx) + (p - 16);
        for (int h = 0; h < Hh; h++) {
            float xv = inr ? xb[h * Wx] : 0.f;
#pragma unroll
            for (int j = 0; j < 8; j++) acc[j] += xv * dws[j * 32 + h];
        }
#pragma unroll
        for (int j = 0; j < 8; j++) Ys[j * WP + p] = acc[j];
    }
    __syncthreads();
    // Phase B: register-blocked 4 consecutive w per thread, ds_read_b128
    float* dwout = ws + OFF_DWOUT;
    int lane = tid & 63;
    int wt = tid * 4;
    for (int j = 0; j < 8; j++) {
        int gl = j >> 1;
        float a = a1s[gl], bb = b1s[gl] * Dv[j];
        float wr[32];
#pragma unroll
        for (int k = 0; k < 32; k++) wr[k] = w1s[gl * 32 + k];
        float y[36];
        const float4* yp = (const float4*)(Ys + j * WP + wt);
#pragma unroll
        for (int q = 0; q < 9; q++) {
            float4 t4 = yp[q];
            y[4 * q] = t4.x; y[4 * q + 1] = t4.y; y[4 * q + 2] = t4.z; y[4 * q + 3] = t4.w;
        }
        float ls1 = 0.f, ls2 = 0.f;
        float outv[4];
#pragma unroll
        for (int m = 0; m < 4; m++) {
            float s = 0.f;
#pragma unroll
            for (int k = 0; k < 32; k++) s += wr[k] * y[m + k];
            float val = a * s + bb;
            outv[m] = val;
            ls1 += val; ls2 += val * val;
        }
        *((float4*)(dwout + (b * 32 + ocb + j) * 1024 + wt)) =
            make_float4(outv[0], outv[1], outv[2], outv[3]);
        if (tid == 0) {  // tail w=1024: stats only, never stored/read downstream
            float s = 0.f;
#pragma unroll
            for (int k = 0; k < 32; k++) s += wr[k] * Ys[j * WP + 1024 + k];
            float val = a * s + bb;
            ls1 += val; ls2 += val * val;
        }
#pragma unroll
        for (int off = 32; off > 0; off >>= 1) {
            ls1 += __shfl_down(ls1, off);
            ls2 += __shfl_down(ls2, off);
        }
        if (lane == 0) { atomicAdd(&st[j], ls1); atomicAdd(&st[8 + j], ls2); }
    }
    __syncthreads();
    if (tid < 8) atomicAdd(&ws[OFF_S1_2 + ocb + tid], st[tid]);
    else if (tid < 16) atomicAdd(&ws[OFF_S2_2 + ocb + tid - 8], st[tid]);
}

// ---------------- K3: fused BN2+ELU+pool4 + ec1 + b2c1 per (b,c) ----------------
// grid (128, 32), 64 threads. dwout row -> pooled(256) -> e1(257) -> e2(258) -> ws.
__global__ __launch_bounds__(64) void k_pe(const float* __restrict__ ec1w,
                                           const float* __restrict__ bc1w,
                                           const float* __restrict__ bn2w,
                                           const float* __restrict__ bn2b,
                                           float* __restrict__ ws) {
    __shared__ float ins[272];   // pooled padded +-8
    __shared__ float e1p[288];   // e1 padded +-8 (e1 valid w 0..256 at [8..264])
    int b = blockIdx.x, c = blockIdx.y;
    int t = threadIdx.x;
    if (t < 8) { ins[t] = 0.f; ins[264 + t] = 0.f; e1p[t] = 0.f; }
    if (t < 23) e1p[265 + t] = 0.f;
    float mean = ws[OFF_S1_2 + c] / N2f;
    float var = fmaxf(ws[OFF_S2_2 + c] / N2f - mean * mean, 0.f);
    float a = bn2w[c] / sqrtf(var + 1e-3f);
    float bb = bn2b[c] - mean * a;
    const float4* dr = (const float4*)(ws + OFF_DWOUT + (b * 32 + c) * 1024);
#pragma unroll
    for (int q = 0; q < 4; q++) {
        float4 v4 = dr[q * 64 + t];
        ins[8 + q * 64 + t] = 0.25f * (eluf(a * v4.x + bb) + eluf(a * v4.y + bb) +
                                       eluf(a * v4.z + bb) + eluf(a * v4.w + bb));
    }
    __syncthreads();
    float ek[16], bk[16];
#pragma unroll
    for (int k = 0; k < 16; k++) { ek[k] = ec1w[c * 16 + k]; bk[k] = bc1w[c * 16 + k]; }
    for (int w = t; w < 257; w += 64) {
        float s = 0.f;
#pragma unroll
        for (int k = 0; k < 16; k++) s += ins[w + k] * ek[k];
        e1p[8 + w] = s;
    }
    __syncthreads();
    float* e2r = ws + OFF_E2 + (b * 32 + c) * 258;
    for (int w = t; w < 258; w += 64) {
        float s = 0.f;
#pragma unroll
        for (int k = 0; k < 16; k++) s += e1p[w + k] * bk[k];
        e2r[w] = s;
    }
}

// ---------------- K4: b2c2 (1x1 dense) + BN3 stats ----------------
// grid (128, 2): batch b, w-half [129*y, 129*y+129)
__global__ __launch_bounds__(256) void k_sep2(const float* __restrict__ bc2w,
                                              float* __restrict__ ws) {
    __shared__ float es[32 * 129];
    __shared__ float bs[1056];   // stride 33 to avoid bank conflicts
    int b = blockIdx.x;
    int wb = blockIdx.y * 129;
    int t = threadIdx.x;
    for (int i = t; i < 1024; i += 256) { int o = i >> 5, cc = i & 31; bs[o * 33 + cc] = bc2w[i]; }
    const float* e2b = ws + OFF_E2 + b * 8256;
    for (int i = t; i < 4128; i += 256) {
        int cc = i / 129, wl = i - cc * 129;
        es[i] = e2b[cc * 258 + wb + wl];
    }
    __syncthreads();
    int o = t >> 3, w0 = t & 7;
    float wr[32];
#pragma unroll
    for (int cc = 0; cc < 32; cc++) wr[cc] = bs[o * 33 + cc];
    float s1 = 0.f, s2 = 0.f;
    float* c3r = ws + OFF_C3 + (b * 32 + o) * 258 + wb;
    for (int wl = w0; wl < 129; wl += 8) {
        float s = 0.f;
#pragma unroll
        for (int cc = 0; cc < 32; cc++) s += es[cc * 129 + wl] * wr[cc];
        c3r[wl] = s;
        s1 += s; s2 += s * s;
    }
    s1 += __shfl_down(s1, 4, 8); s1 += __shfl_down(s1, 2, 8); s1 += __shfl_down(s1, 1, 8);
    s2 += __shfl_down(s2, 4, 8); s2 += __shfl_down(s2, 2, 8); s2 += __shfl_down(s2, 1, 8);
    if (w0 == 0) {
        atomicAdd(&ws[OFF_S1_3 + o], s1);
        atomicAdd(&ws[OFF_S2_3 + o], s2);
    }
}

// ---------------- K5: BN3+ELU+pool4 + normalize + lift + lc1 (o=1..32) -> pts ----------------
__global__ __launch_bounds__(256, 1) void k_head(const float* __restrict__ bn3w,
                                                 const float* __restrict__ bn3b,
                                                 const float* __restrict__ lc1w,
                                                 const int* __restrict__ domains,
                                                 float* __restrict__ ws) {
    __shared__ float q[2048];        // [c][w] 32x64
    __shared__ float lc1s[1089];
    __shared__ float psum[33];
    __shared__ float ssyp[4][64];
    __shared__ float a3s[32], b3s[32];
    int tid = threadIdx.x;
    int b = blockIdx.x;
    if (tid < 32) {
        float mean = ws[OFF_S1_3 + tid] / N3f;
        float var = fmaxf(ws[OFF_S2_3 + tid] / N3f - mean * mean, 0.f);
        float a = bn3w[tid] / sqrtf(var + 1e-3f);
        a3s[tid] = a;
        b3s[tid] = bn3b[tid] - mean * a;
    }
    for (int i = tid; i < 1089; i += 256) lc1s[i] = lc1w[i];
    __syncthreads();
    const float* c3 = ws + OFF_C3 + b * 8256;
    for (int idx = tid; idx < 2048; idx += 256) {
        int c = idx >> 6, wp = idx & 63;
        float a = a3s[c], bb = b3s[c];
        float acc = 0.f;
#pragma unroll
        for (int j = 0; j < 4; j++) {
            float e = a * c3[c * 258 + wp * 4 + j] + bb;
            acc += eluf(e);
        }
        q[idx] = 0.25f * acc;
    }
    __syncthreads();
    int w = tid & 63, sub = tid >> 6;
    float qv[32];
    float ssq = 0.f;
#pragma unroll
    for (int c = 0; c < 32; c++) { qv[c] = q[c * 64 + w]; ssq += qv[c] * qv[c]; }
    float inv = 1.f / fmaxf(sqrtf(ssq), 1e-12f);
    float ss2 = 0.f;
#pragma unroll
    for (int c = 0; c < 32; c++) { qv[c] *= inv; ss2 += qv[c] * qv[c]; }
    float t = sqrtf(1.f + ss2);
    int o0 = 1 + sub * 8;
    float p[8];
    float ssy_part = 0.f;
#pragma unroll
    for (int i = 0; i < 8; i++) {
        int o = o0 + i;
        float s = lc1s[o * 33] * t;
#pragma unroll
        for (int c = 0; c < 32; c++) s += lc1s[o * 33 + 1 + c] * qv[c];
        p[i] = s;
        ssy_part += s * s;
    }
    ssyp[sub][w] = ssy_part;
    float* pr = ws + OFF_PTS + (b * 64 + w) * 33;
#pragma unroll
    for (int i = 0; i < 8; i++) pr[o0 + i] = p[i];
    __syncthreads();
    float yt = 0.f;
    if (sub == 0) {
        float ssy = ssyp[0][w] + ssyp[1][w] + ssyp[2][w] + ssyp[3][w];
        yt = sqrtf(1.f + ssy);
        pr[0] = yt;
    }
#pragma unroll
    for (int i = 0; i < 8; i++) {
        float vv = p[i];
#pragma unroll
        for (int off = 32; off > 0; off >>= 1) vv += __shfl_down(vv, off);
        if (w == 0) psum[o0 + i] = vv;
    }
    {
        float vv = yt;
#pragma unroll
        for (int off = 32; off > 0; off >>= 1) vv += __shfl_down(vv, off);
        if (w == 0 && sub == 0) psum[0] = vv;
    }
    __syncthreads();
    int dom = domains[b];
    if (tid < 33) atomicAdd(&ws[OFF_SEG + dom * 33 + tid], psum[tid]);
    if (tid == 64) atomicAdd(&ws[OFF_CNT + dom], 64.f);
}

// ---------------- K6: per-domain mean mu ----------------
__global__ void k_mu(float* __restrict__ ws) {
    int d = threadIdx.x;
    if (d < 4) {
        float cnt = fmaxf(ws[OFF_CNT + d], 1.f);
        float sv[33];
        float s0 = ws[OFF_SEG + d * 33] / cnt;
        sv[0] = s0;
        float sum = 0.f;
        for (int c = 1; c < 33; c++) {
            sv[c] = ws[OFF_SEG + d * 33 + c] / cnt;
            sum += sv[c] * sv[c];
        }
        float mk = -s0 * s0 + sum;
        float dn = sqrtf(fmaxf(fabsf(mk), 1e-8f));
        for (int c = 0; c < 33; c++) ws[OFF_MU + d * 33 + c] = sv[c] / dn;
    }
}

// ---------------- K7: log-map at mu, transport to origin, dist^2 sums ----------------
__global__ __launch_bounds__(64, 1) void k_tangent(const int* __restrict__ domains,
                                                   float* __restrict__ ws) {
    int b = blockIdx.x;
    int w = threadIdx.x;
    int dom = domains[b];
    const float* mu = ws + OFF_MU + dom * 33;
    const float* pr = ws + OFF_PTS + (b * 64 + w) * 33;
    float m[33], p[33];
#pragma unroll
    for (int c = 0; c < 33; c++) { m[c] = mu[c]; p[c] = pr[c]; }
    float ip = -m[0] * p[0];
#pragma unroll
    for (int c = 1; c < 33; c++) ip += m[c] * p[c];
    float z = fmaxf(-ip, 1.f + 1e-7f);
    float dist = acoshf(z);
    float u[33];
#pragma unroll
    for (int c = 0; c < 33; c++) u[c] = p[c] + ip * m[c];
    float mk = -u[0] * u[0];
#pragma unroll
    for (int c = 1; c < 33; c++) mk += u[c] * u[c];
    float un = sqrtf(fmaxf(mk, 1e-8f));
    float r = dist / un;
    float v0 = r * u[0];
    float coef = -v0 / (1.f + m[0]);
    float* vo = ws + OFF_VO + (b * 64 + w) * 33;
    vo[0] = v0 + coef * (m[0] + 1.f);
#pragma unroll
    for (int c = 1; c < 33; c++) vo[c] = r * u[c] + coef * m[c];
    float dsq = dist * dist;
#pragma unroll
    for (int off = 32; off > 0; off >>= 1) dsq += __shfl_down(dsq, off);
    if (w == 0) atomicAdd(&ws[OFF_DSQ + dom], dsq);
}

// ---------------- K8: scale, transport to beta, expmap, L-ELU, L-pool, MLR ----------------
__global__ __launch_bounds__(64, 1) void k_final(const int* __restrict__ domains,
                                                 const float* __restrict__ beta,
                                                 const float* __restrict__ gamma,
                                                 const float* __restrict__ mlr_a,
                                                 const float* __restrict__ mlr_z,
                                                 float* __restrict__ ws,
                                                 float* __restrict__ out) {
    __shared__ float he[64 * 33];
    __shared__ float hp[16 * 33];
    int b = blockIdx.x;
    int w = threadIdx.x;
    int dom = domains[b];
    float cnt = fmaxf(ws[OFF_CNT + dom], 1.f);
    float var = ws[OFF_DSQ + dom] / cnt;
    float sc = gamma[0] / sqrtf(var + 1e-5f);
    float bt[33];
#pragma unroll
    for (int c = 0; c < 33; c++) bt[c] = beta[c];
    const float* vo = ws + OFF_VO + (b * 64 + w) * 33;
    float v[33];
#pragma unroll
    for (int c = 0; c < 33; c++) v[c] = vo[c] * sc;
    float mb = -bt[0] * v[0];
#pragma unroll
    for (int c = 1; c < 33; c++) mb += bt[c] * v[c];
    float coef = mb / (1.f + bt[0]);
    v[0] += coef * (1.f + bt[0]);
#pragma unroll
    for (int c = 1; c < 33; c++) v[c] += coef * bt[c];
    float mk = -v[0] * v[0];
#pragma unroll
    for (int c = 1; c < 33; c++) mk += v[c] * v[c];
    float vn = sqrtf(fmaxf(mk, 1e-8f));
    float ch = coshf(vn), sh = sinhf(vn) / vn;
    float ss = 0.f;
#pragma unroll
    for (int c = 1; c < 33; c++) {
        float y = ch * bt[c] + sh * v[c];
        float s = eluf(y);
        he[w * 33 + c] = s;
        ss += s * s;
    }
    he[w * 33] = sqrtf(1.f + ss);
    __syncthreads();
    if (w < 16) {
        float tmp[33];
        float mk2;
        {
            float a0 = 0.25f * (he[(4 * w) * 33] + he[(4 * w + 1) * 33] +
                                he[(4 * w + 2) * 33] + he[(4 * w + 3) * 33]);
            tmp[0] = a0;
            mk2 = -a0 * a0;
        }
#pragma unroll
        for (int c = 1; c < 33; c++) {
            float a = 0.25f * (he[(4 * w) * 33 + c] + he[(4 * w + 1) * 33 + c] +
                               he[(4 * w + 2) * 33 + c] + he[(4 * w + 3) * 33 + c]);
            tmp[c] = a;
            mk2 += a * a;
        }
        float dd = sqrtf(fmaxf(fabsf(mk2), 1e-8f));
#pragma unroll
        for (int c = 0; c < 33; c++) hp[w * 33 + c] = tmp[c] / dd;
    }
    __syncthreads();
    float ssq = 0.f, sdz = 0.f, zz = 0.f;
    for (int j = w; j < 512; j += 64) {
        float val = hp[(j >> 5) * 33 + 1 + (j & 31)];
        float zv = mlr_z[j];
        ssq += val * val;
        sdz += val * zv;
        zz += zv * zv;
        out[128 + b * 513 + 1 + j] = val;
    }
#pragma unroll
    for (int off = 32; off > 0; off >>= 1) {
        ssq += __shfl_down(ssq, off);
        sdz += __shfl_down(sdz, off);
        zz += __shfl_down(zz, off);
    }
    if (w == 0) {
        float nz = sqrtf(zz);
        float a = mlr_a[0];
        float cha = coshf(a);
        float wt = sinhf(a) * nz;
        float cn = cha * nz;
        float bet = sqrtf(fmaxf(cn * cn - wt * wt, 1e-8f));
        float ft = sqrtf(1.f + ssq);
        float alpha = -wt * ft + cha * sdz;
        out[128 + b * 513] = ft;
        out[b] = bet * asinhf(alpha / bet);
    }
}

extern "C" void kernel_launch(void* const* d_in, const int* in_sizes, int n_in,
                              void* d_out, int out_size, void* d_ws, size_t ws_size,
                              hipStream_t stream) {
    const float* x       = (const float*)d_in[0];
    const int*   domains = (const int*)d_in[1];
    const float* conv1_w = (const float*)d_in[2];
    const float* bn1_w   = (const float*)d_in[3];
    const float* bn1_b   = (const float*)d_in[4];
    const float* dw_w    = (const float*)d_in[5];
    const float* bn2_w   = (const float*)d_in[6];
    const float* bn2_b   = (const float*)d_in[7];
    const float* ec1_w   = (const float*)d_in[8];
    const float* b2c1_w  = (const float*)d_in[9];
    const float* b2c2_w  = (const float*)d_in[10];
    const float* bn3_w   = (const float*)d_in[11];
    const float* bn3_b   = (const float*)d_in[12];
    const float* lc1_w   = (const float*)d_in[13];
    const float* bn_beta = (const float*)d_in[14];
    const float* bn_gamma= (const float*)d_in[15];
    const float* mlr_a   = (const float*)d_in[16];
    const float* mlr_z   = (const float*)d_in[17];
    float* out = (float*)d_out;
    float* ws  = (float*)d_ws;

    hipMemsetAsync(ws, 0, ZERO_N * sizeof(float), stream);
    k_corr<<<256, 256, 0, stream>>>(x, ws);
    k_fold<<<1, 512, 0, stream>>>(conv1_w, bn1_w, bn1_b, ws);
    k_dw<<<dim3(128, 4), 256, 0, stream>>>(x, conv1_w, dw_w, ws);
    k_pe<<<dim3(128, 32), 64, 0, stream>>>(ec1_w, b2c1_w, bn2_w, bn2_b, ws);
    k_sep2<<<dim3(128, 2), 256, 0, stream>>>(b2c2_w, ws);
    k_head<<<Bn, 256, 0, stream>>>(bn3_w, bn3_b, lc1_w, domains, ws);
    k_mu<<<1, 64, 0, stream>>>(ws);
    k_tangent<<<Bn, 64, 0, stream>>>(domains, ws);
    k_final<<<Bn, 64, 0, stream>>>(domains, bn_beta, bn_gamma, mlr_a, mlr_z, ws, out);
}